// Round 19
// baseline (387.234 us; speedup 1.0000x reference)
//
#include <hip/hip_runtime.h>
#include <stdint.h>

#define FEAT_STRIDE_I 16
#define A_NUM 9
#define HH 128
#define WW 128
#define NPIX (HH * WW)            // 16384
#define N_ANCH (NPIX * A_NUM)     // 147456
#define B_NUM 8
#define PRE_NMS 6000
#define POST_NMS 300
#define NMS_THRESH_F 0.7f
#define MIN_SIZE_F 16.0f
#define NEG_INF_F -1e30f

#define NBS 16384                  // 14-bit bins (key>>18)
#define SWS(i) ((i) + ((i) >> 5))  // LDS swizzle
#define SEGL 8192                  // candidate segment cap (cnt ~6500 max)
#define QKEYS (N_ANCH / 4)         // 36864 keys per hist part

#define RT_TILES 94                // ceil(6000/64)
#define GT_TILES 600               // sum_R ceil((94-R)/8): 8-column groups
#define BQWORDS (RT_TILES * RT_TILES * 64)   // 565,504 qwords per batch

// ---- workspace layout (bytes) ----
#define OFF_KEYS    0u             // 8*147456*4 = 4,718,592
#define OFF_BOXES   4718592u       // 8*6000*4*4 = 768,000
#define OFF_PHIST   5486592u       // 8*4*16384*4 = 2,097,152
#define OFF_CNT     7583744u       // thresh[8] + cnt2[8] (512 B, zeroed)
#define OFF_SEG     7584256u       // 8*8192*8 = 524,288
#define OFF_RIDX    8108544u       // 8*6000*4 = 192,000
#define OFF_MASK    8300544u       // 36,192,256 -> end 44,492,800
#define MASK_BYTES ((size_t)B_NUM * BQWORDS * 8)

__device__ __forceinline__ unsigned sortable_f32(float f) {
    unsigned u = __float_as_uint(f);
    return (u & 0x80000000u) ? ~u : (u | 0x80000000u);
}

// Decode one anchor's box exactly in the reference's op order.
__device__ __forceinline__ void decode_box(
    int b, int idx,
    const float* __restrict__ deltas, const float* __restrict__ im_info,
    const float* __restrict__ anchors,
    float& x1, float& y1, float& x2, float& y2, bool& valid)
{
    int a   = idx % A_NUM;
    int pix = idx / A_NUM;
    int w   = pix & (WW - 1);
    int h   = pix >> 7;

    float a0 = anchors[a * 4 + 0];
    float a1 = anchors[a * 4 + 1];
    float a2 = anchors[a * 4 + 2];
    float a3 = anchors[a * 4 + 3];

    float aw = __fadd_rn(__fsub_rn(a2, a0), 1.0f);
    float ah = __fadd_rn(__fsub_rn(a3, a1), 1.0f);
    float sx = (float)(w * FEAT_STRIDE_I);
    float sy = (float)(h * FEAT_STRIDE_I);
    float acx = __fadd_rn(__fadd_rn(sx, a0), __fmul_rn(0.5f, aw));
    float acy = __fadd_rn(__fadd_rn(sy, a1), __fmul_rn(0.5f, ah));

    size_t base = ((size_t)b * 36 + 4 * a) * NPIX + pix;
    float dx = deltas[base];
    float dy = deltas[base + NPIX];
    float dw = deltas[base + 2 * (size_t)NPIX];
    float dh = deltas[base + 3 * (size_t)NPIX];

    float pcx = __fadd_rn(__fmul_rn(dx, aw), acx);
    float pcy = __fadd_rn(__fmul_rn(dy, ah), acy);
    float pw  = __fmul_rn(expf(dw), aw);
    float ph  = __fmul_rn(expf(dh), ah);

    float hx = __fmul_rn(0.5f, pw);
    float hy = __fmul_rn(0.5f, ph);
    x1 = __fsub_rn(pcx, hx);
    y1 = __fsub_rn(pcy, hy);
    x2 = __fadd_rn(pcx, hx);
    y2 = __fadd_rn(pcy, hy);

    float im_h = im_info[b * 3 + 0];
    float im_w = im_info[b * 3 + 1];
    float sc   = im_info[b * 3 + 2];
    float wmax = __fsub_rn(im_w, 1.0f);
    float hmax = __fsub_rn(im_h, 1.0f);

    x1 = fminf(fmaxf(x1, 0.0f), wmax);
    y1 = fminf(fmaxf(y1, 0.0f), hmax);
    x2 = fminf(fmaxf(x2, 0.0f), wmax);
    y2 = fminf(fmaxf(y2, 0.0f), hmax);

    float min_sz = __fmul_rn(MIN_SIZE_F, sc);
    valid = (__fadd_rn(__fsub_rn(x2, x1), 1.0f) >= min_sz) &&
            (__fadd_rn(__fsub_rn(y2, y1), 1.0f) >= min_sz);
}

// K1: decode + masked score -> sortable key. Pure streaming, no atomics.
__global__ void k_decode(
    const float* __restrict__ scores, const float* __restrict__ deltas,
    const float* __restrict__ im_info, const float* __restrict__ anchors,
    unsigned* __restrict__ keys)
{
    int gt = blockIdx.x * blockDim.x + threadIdx.x;
    if (gt >= B_NUM * N_ANCH) return;
    int pix  = gt & (NPIX - 1);
    int rest = gt >> 14;
    int a = rest % A_NUM;
    int b = rest / A_NUM;
    int idx = pix * A_NUM + a;

    float x1, y1, x2, y2; bool valid;
    decode_box(b, idx, deltas, im_info, anchors, x1, y1, x2, y2, valid);

    float s = scores[((size_t)b * 18 + 9 + a) * NPIX + pix];
    if (!valid) s = NEG_INF_F;
    keys[gt] = sortable_f32(s);
}

// K2: partial histograms — 4 blocks per batch, each hists one quarter of
// the keys in a private LDS 16384-bin histogram (staged uint4 loads).
__global__ __launch_bounds__(1024) void k_hist_part(
    const unsigned* __restrict__ keys, unsigned* __restrict__ phist)
{
    __shared__ unsigned h[SWS(NBS - 1) + 2];   // 16896 words = 67.6 KB
    int b = blockIdx.x >> 2;
    int p = blockIdx.x & 3;
    int t = threadIdx.x;

    for (int i = t; i < SWS(NBS - 1) + 2; i += 1024) h[i] = 0u;
    __syncthreads();

    const uint4* kb4 = (const uint4*)(keys + (size_t)b * N_ANCH + p * QKEYS);
    uint4 v[9];
    #pragma unroll
    for (int k = 0; k < 9; ++k) v[k] = kb4[t + 1024 * k];
    #pragma unroll
    for (int k = 0; k < 9; ++k) {
        atomicAdd(&h[SWS(v[k].x >> 18)], 1u);
        atomicAdd(&h[SWS(v[k].y >> 18)], 1u);
        atomicAdd(&h[SWS(v[k].z >> 18)], 1u);
        atomicAdd(&h[SWS(v[k].w >> 18)], 1u);
    }
    __syncthreads();

    unsigned* ph = phist + (size_t)blockIdx.x * NBS;
    for (int i = t; i < NBS; i += 1024) ph[i] = h[SWS(i)];
}

// K3: per batch — sum 4 partials, suffix-scan 16384 bins, find and write
// threshold T only (rank is now handled by a sort; no binbase needed).
__global__ __launch_bounds__(1024) void k_thresh2(
    const unsigned* __restrict__ phist, unsigned* __restrict__ thresh)
{
    __shared__ unsigned h[SWS(NBS - 1) + 2];
    __shared__ unsigned csum[1024];
    __shared__ unsigned sT;

    int b = blockIdx.x;
    int t = threadIdx.x;
    if (t == 0) sT = 0;

    const unsigned* ph = phist + (size_t)b * 4 * NBS;
    for (int i = t; i < NBS; i += 1024) {
        unsigned s0 = ph[i];
        unsigned s1 = ph[NBS + i];
        unsigned s2 = ph[2 * NBS + i];
        unsigned s3 = ph[3 * NBS + i];
        h[SWS(i)] = s0 + s1 + s2 + s3;
    }
    __syncthreads();

    // chunk sums (16 bins/thread) + inclusive suffix scan
    int base = t * 16;
    unsigned s = 0;
    for (int u = 0; u < 16; ++u) s += h[SWS(base + u)];
    csum[t] = s;
    __syncthreads();
    for (int off = 1; off < 1024; off <<= 1) {
        unsigned v = (t + off < 1024) ? csum[t + off] : 0u;
        __syncthreads();
        csum[t] += v;
        __syncthreads();
    }
    unsigned before = csum[t] - s;

    unsigned acc = before;
    for (int bin = base + 15; bin >= base; --bin) {
        unsigned hh = h[SWS(bin)];
        if (acc + hh >= PRE_NMS) { atomicMax(&sT, (unsigned)bin); break; }
        acc += hh;
    }
    __syncthreads();
    if (t == 0) thresh[b] = sT;
}

// K4: block-aggregated scatter of passing keys (bin >= T) into a per-batch
// append buffer (one global atomic per 256-thread block). Order within the
// buffer is nondeterministic; K5a's sort restores the deterministic total
// order (keys unique via ~idx).
__global__ void k_scatter(
    const unsigned* __restrict__ keys, const unsigned* __restrict__ thresh,
    unsigned* __restrict__ cnt2, unsigned long long* __restrict__ seg)
{
    int gt = blockIdx.x * blockDim.x + threadIdx.x;
    int pix  = gt & (NPIX - 1);
    int rest = gt >> 14;
    int a = rest % A_NUM;
    int b = rest / A_NUM;

    unsigned key = keys[gt];
    bool pass = (key >> 18) >= thresh[b];

    unsigned long long mask = __ballot(pass);
    int lane = threadIdx.x & 63;
    int wid  = threadIdx.x >> 6;
    unsigned wrank = (unsigned)__popcll(mask & ((1ULL << lane) - 1ULL));
    unsigned wtot  = (unsigned)__popcll(mask);

    __shared__ unsigned wbase[4];
    __shared__ unsigned blockbase;
    if (lane == 0) wbase[wid] = wtot;
    __syncthreads();
    if (threadIdx.x == 0) {
        unsigned s0 = wbase[0], s1 = wbase[1], s2 = wbase[2], s3 = wbase[3];
        unsigned tot = s0 + s1 + s2 + s3;
        blockbase = tot ? atomicAdd(&cnt2[b], tot) : 0u;
        wbase[0] = 0; wbase[1] = s0; wbase[2] = s0 + s1; wbase[3] = s0 + s1 + s2;
    }
    __syncthreads();

    if (pass) {
        unsigned pos = blockbase + wbase[wid] + wrank;
        if (pos < SEGL) {
            unsigned idx = (unsigned)(pix * A_NUM + a);
            seg[(size_t)b * SEGL + pos] =
                ((unsigned long long)key << 32) | (unsigned long long)(0xFFFFFFFFu - idx);
        }
    }
}

// K5a: full LDS bitonic sort (descending) of the 8192-slot candidate
// buffer; sorted position IS the rank. Replaces the per-candidate segment
// scan (measured 87-105us across two variants: the ~500-candidate
// threshold bin each serially scanning ~500 entries was the floor).
// 91 phases x ~4 compare-exchanges/thread ~= 15-25us.
__global__ __launch_bounds__(1024) void k_sortrank(
    const unsigned long long* __restrict__ seg, const unsigned* __restrict__ cnt2,
    unsigned* __restrict__ ridx)
{
    __shared__ unsigned long long sl[SEGL];   // 64 KB
    int b = blockIdx.x;
    int t = threadIdx.x;
    unsigned n = cnt2[b];
    if (n > SEGL) n = SEGL;

    const unsigned long long* S = seg + (size_t)b * SEGL;
    for (int p = t; p < SEGL; p += 1024)
        sl[p] = (p < (int)n) ? S[p] : 0ULL;   // pad zeros sort to the tail
    __syncthreads();

    for (unsigned k = 2; k <= SEGL; k <<= 1) {
        for (unsigned j = k >> 1; j > 0; j >>= 1) {
            for (unsigned i = t; i < SEGL; i += 1024) {
                unsigned l = i ^ j;
                if (l > i) {
                    unsigned long long a = sl[i], c = sl[l];
                    bool desc = ((i & k) == 0);
                    if (desc ? (a < c) : (a > c)) { sl[i] = c; sl[l] = a; }
                }
            }
            __syncthreads();
        }
    }

    for (int r = t; r < PRE_NMS; r += 1024)
        ridx[(size_t)b * PRE_NMS + r] =
            0xFFFFFFFFu - (unsigned)(sl[r] & 0xFFFFFFFFull);
}

// K5b: decode one box per output rank — 48K threads across all CUs so the
// 4-line scattered deltas gather (~12 MB of 64B lines) is latency-hidden.
__global__ void k_decode2(
    const unsigned* __restrict__ ridx,
    const float* __restrict__ deltas, const float* __restrict__ im_info,
    const float* __restrict__ anchors, float* __restrict__ boxes)
{
    int gt = blockIdx.x * blockDim.x + threadIdx.x;
    if (gt >= B_NUM * PRE_NMS) return;
    int b = gt / PRE_NMS;
    int idx = (int)ridx[gt];
    float x1, y1, x2, y2; bool v;
    decode_box(b, idx, deltas, im_info, anchors, x1, y1, x2, y2, v);
    *(float4*)(boxes + (size_t)gt * 4) = make_float4(x1, y1, x2, y2);
}

// One row of a 64x64 suppression block: inter/uni in the reference's exact
// op order; division eliminated except in the proven +-6e-7*uni band
// (round-6 proof; validated absmax=0). Returns the 64-bit suppress mask.
__device__ __forceinline__ unsigned long long iou_row(
    float4 bi, float ia, float jx1, float jy1, float jx2, float jy2, float ja)
{
    float xx1 = fmaxf(bi.x, jx1);
    float yy1 = fmaxf(bi.y, jy1);
    float xx2 = fminf(bi.z, jx2);
    float yy2 = fminf(bi.w, jy2);
    float iw = fmaxf(0.0f, __fadd_rn(__fsub_rn(xx2, xx1), 1.0f));
    float ih = fmaxf(0.0f, __fadd_rn(__fsub_rn(yy2, yy1), 1.0f));
    float inter = __fmul_rn(iw, ih);
    float uni = __fsub_rn(__fadd_rn(ia, ja), inter);
    float diff = __fsub_rn(inter, __fmul_rn(NMS_THRESH_F, uni));
    unsigned long long sup = __ballot(diff > 0.0f);
    unsigned long long band = __ballot(fabsf(diff) <= __fmul_rn(6e-7f, uni));
    if (band) {   // rare; wave-uniform branch
        unsigned long long supd = __ballot(__fdiv_rn(inter, uni) > NMS_THRESH_F);
        sup = (sup & ~band) | (supd & band);
    }
    return sup;
}

// K6: upper-triangular IoU suppression bitmask, blocked layout
// mask[b][R][C][64] (u64). 256-thread blocks: 4 waves share one row tile
// (LDS loaded once); each wave owns one column PAIR of an 8-column group.
__global__ __launch_bounds__(256) void k_iou_mask(
    const float* __restrict__ boxes, unsigned long long* __restrict__ mask)
{
    int bid = blockIdx.x;
    int b = bid / GT_TILES;
    int g = bid - b * GT_TILES;
    int R = 0;
    while (g >= ((RT_TILES - R + 7) >> 3)) { g -= (RT_TILES - R + 7) >> 3; ++R; }

    int wave = threadIdx.x >> 6;
    int lane = threadIdx.x & 63;
    const float* Bb = boxes + (size_t)b * PRE_NMS * 4;

    __shared__ float4 rb4[64];
    __shared__ float rba[64];
    if (threadIdx.x < 64) {
        int il = R * 64 + threadIdx.x;
        float4 rv = make_float4(0.f, 0.f, -1.f, -1.f);
        if (il < PRE_NMS) rv = *(const float4*)(Bb + 4 * (size_t)il);
        rb4[threadIdx.x] = rv;
        rba[threadIdx.x] = __fmul_rn(__fadd_rn(__fsub_rn(rv.z, rv.x), 1.0f),
                                     __fadd_rn(__fsub_rn(rv.w, rv.y), 1.0f));
    }
    __syncthreads();

    int C1 = R + g * 8 + wave * 2;
    int C2 = C1 + 1;
    if (C1 >= RT_TILES) return;   // tail waves idle (no barriers below)

    float j1x1 = 0.f, j1y1 = 0.f, j1x2 = -1.f, j1y2 = -1.f;
    float j2x1 = 0.f, j2y1 = 0.f, j2x2 = -1.f, j2y2 = -1.f;
    int j1 = C1 * 64 + lane;
    int j2 = C2 * 64 + lane;
    if (j1 < PRE_NMS) {
        float4 v = *(const float4*)(Bb + 4 * (size_t)j1);
        j1x1 = v.x; j1y1 = v.y; j1x2 = v.z; j1y2 = v.w;
    }
    if (C2 < RT_TILES && j2 < PRE_NMS) {
        float4 v = *(const float4*)(Bb + 4 * (size_t)j2);
        j2x1 = v.x; j2y1 = v.y; j2x2 = v.z; j2y2 = v.w;
    }
    float j1a = __fmul_rn(__fadd_rn(__fsub_rn(j1x2, j1x1), 1.0f),
                          __fadd_rn(__fsub_rn(j1y2, j1y1), 1.0f));
    float j2a = __fmul_rn(__fadd_rn(__fsub_rn(j2x2, j2x1), 1.0f),
                          __fadd_rn(__fsub_rn(j2y2, j2y1), 1.0f));

    unsigned long long w1 = 0ULL, w2 = 0ULL;
    if (C1 == R) {   // diagonal tile (g==0, wave==0 only)
        #pragma unroll 4
        for (int ri = 0; ri < 64; ++ri) {
            float4 bi = rb4[ri];
            float ia = rba[ri];
            unsigned long long s1 = iou_row(bi, ia, j1x1, j1y1, j1x2, j1y2, j1a)
                                    & (0xFFFFFFFFFFFFFFFEull << ri);
            unsigned long long s2 = iou_row(bi, ia, j2x1, j2y1, j2x2, j2y2, j2a);
            w1 = (lane == ri) ? s1 : w1;
            w2 = (lane == ri) ? s2 : w2;
        }
    } else {
        #pragma unroll 4
        for (int ri = 0; ri < 64; ++ri) {
            float4 bi = rb4[ri];
            float ia = rba[ri];
            unsigned long long s1 = iou_row(bi, ia, j1x1, j1y1, j1x2, j1y2, j1a);
            unsigned long long s2 = iou_row(bi, ia, j2x1, j2y1, j2x2, j2y2, j2a);
            w1 = (lane == ri) ? s1 : w1;
            w2 = (lane == ri) ? s2 : w2;
        }
    }

    unsigned long long* Mb = mask + (size_t)b * BQWORDS;
    Mb[(size_t)(R * RT_TILES + C1) * 64 + lane] = w1;
    if (C2 < RT_TILES)
        Mb[(size_t)(R * RT_TILES + C2) * 64 + lane] = w2;
}

// K7: serial greedy scan + fused output write. One wave per batch.
// 16-deep unconditional prefetch (static register slots); C<R(i) words
// skipped (exec-masked; zeros replace harmless garbage).
__global__ __launch_bounds__(64) void k_nms_scan(
    const unsigned long long* __restrict__ mask,
    const float* __restrict__ boxes, float* __restrict__ out)
{
    const int b = blockIdx.x;
    const int l = threadIdx.x;
    __shared__ unsigned long long supp[RT_TILES];
    __shared__ int klist[POST_NMS];
    supp[l] = 0ULL;
    if (l < RT_TILES - 64) supp[l + 64] = 0ULL;
    __syncthreads();

    const unsigned long long* __restrict__ M = mask + (size_t)b * BQWORDS;
    int kept = 0;
    unsigned long long curw = 0; int curwi = -1;

#define LOADROW(p0, p1, i) { \
        int _i = ((i) < PRE_NMS) ? (i) : (PRE_NMS - 1); \
        int _R = _i >> 6; \
        const unsigned long long* _r = M + (size_t)(_R * RT_TILES) * 64 + (_i & 63); \
        p0 = 0ULL; p1 = 0ULL; \
        if (l >= _R) p0 = _r[l * 64]; \
        if (l < RT_TILES - 64 && 64 + l >= _R) p1 = _r[(64 + l) * 64]; }

#define STEP(i, p0, p1) { \
        if (kept < POST_NMS) { \
            int _wi = (i) >> 6; \
            if (_wi != curwi) { curw = supp[_wi]; curwi = _wi; } \
            if (!((curw >> ((i) & 63)) & 1ULL)) { \
                if (l == 0) klist[kept] = (i); \
                supp[l] |= p0; \
                if (l < RT_TILES - 64) supp[l + 64] |= p1; \
                ++kept; curwi = -1; \
            } \
        } }

    unsigned long long p[16][2];
    #pragma unroll
    for (int k = 0; k < 16; ++k) { LOADROW(p[k][0], p[k][1], k) }

    for (int i = 0; i < PRE_NMS && kept < POST_NMS; i += 16) {
        #pragma unroll
        for (int k = 0; k < 16; ++k) {
            STEP(i + k, p[k][0], p[k][1])
            LOADROW(p[k][0], p[k][1], i + 16 + k)
        }
    }
    __syncthreads();

    for (int k = l; k < POST_NMS; k += 64) {
        size_t o = ((size_t)b * POST_NMS + k) * 5;
        float x1 = 0.f, y1 = 0.f, x2 = 0.f, y2 = 0.f;
        if (k < kept) {
            int idx = klist[k];
            const float4 v = *(const float4*)(boxes + ((size_t)b * PRE_NMS + idx) * 4);
            x1 = v.x; y1 = v.y; x2 = v.z; y2 = v.w;
        }
        out[o + 0] = (float)b;
        out[o + 1] = x1; out[o + 2] = y1; out[o + 3] = x2; out[o + 4] = y2;
    }
#undef LOADROW
#undef STEP
}

// Fallback NMS (used only if ws_size is too small for the bitmask).
__global__ __launch_bounds__(1024) void k_nms_out(
    const float* __restrict__ boxes, float* __restrict__ out)
{
    __shared__ float bx1[PRE_NMS], by1[PRE_NMS], bx2[PRE_NMS], by2[PRE_NMS], bar[PRE_NMS];
    __shared__ unsigned rem[(PRE_NMS + 31) / 32];
    __shared__ int kept_idx[POST_NMS];

    int b = blockIdx.x;
    int t = threadIdx.x;

    for (int p = t; p < PRE_NMS; p += 1024) {
        size_t o = ((size_t)b * PRE_NMS + p) * 4;
        float x1 = boxes[o], y1 = boxes[o + 1], x2 = boxes[o + 2], y2 = boxes[o + 3];
        bx1[p] = x1; by1[p] = y1; bx2[p] = x2; by2[p] = y2;
        bar[p] = __fmul_rn(__fadd_rn(__fsub_rn(x2, x1), 1.0f),
                           __fadd_rn(__fsub_rn(y2, y1), 1.0f));
    }
    for (int p = t; p < (PRE_NMS + 31) / 32; p += 1024) rem[p] = 0u;
    __syncthreads();

    int kept = 0;
    for (int i = 0; i < PRE_NMS && kept < POST_NMS; ++i) {
        if (rem[i >> 5] & (1u << (i & 31))) continue;
        if (t == 0) kept_idx[kept] = i;
        float xi1 = bx1[i], yi1 = by1[i], xi2 = bx2[i], yi2 = by2[i], ai = bar[i];
        for (int j = i + 1 + t; j < PRE_NMS; j += 1024) {
            float xx1 = fmaxf(xi1, bx1[j]);
            float yy1 = fmaxf(yi1, by1[j]);
            float xx2 = fminf(xi2, bx2[j]);
            float yy2 = fminf(yi2, by2[j]);
            float iw = fmaxf(0.0f, __fadd_rn(__fsub_rn(xx2, xx1), 1.0f));
            float ih = fmaxf(0.0f, __fadd_rn(__fsub_rn(yy2, yy1), 1.0f));
            float inter = __fmul_rn(iw, ih);
            if (inter > 0.0f) {
                float uni = __fsub_rn(__fadd_rn(ai, bar[j]), inter);
                float iou = __fdiv_rn(inter, uni);
                if (iou > NMS_THRESH_F) atomicOr(&rem[j >> 5], 1u << (j & 31));
            }
        }
        ++kept;
        __syncthreads();
    }

    for (int k = t; k < POST_NMS; k += 1024) {
        size_t o = ((size_t)b * POST_NMS + k) * 5;
        out[o] = (float)b;
        if (k < kept) {
            int ii = kept_idx[k];
            out[o + 1] = bx1[ii]; out[o + 2] = by1[ii];
            out[o + 3] = bx2[ii]; out[o + 4] = by2[ii];
        } else {
            out[o + 1] = 0.0f; out[o + 2] = 0.0f; out[o + 3] = 0.0f; out[o + 4] = 0.0f;
        }
    }
}

extern "C" void kernel_launch(void* const* d_in, const int* in_sizes, int n_in,
                              void* d_out, int out_size, void* d_ws, size_t ws_size,
                              hipStream_t stream)
{
    const float* scores  = (const float*)d_in[0];
    const float* deltas  = (const float*)d_in[1];
    const float* im_info = (const float*)d_in[2];
    const float* anchors = (const float*)d_in[3];
    float* out = (float*)d_out;
    char* ws = (char*)d_ws;

    unsigned* keys             = (unsigned*)(ws + OFF_KEYS);
    float* boxes               = (float*)(ws + OFF_BOXES);
    unsigned* phist            = (unsigned*)(ws + OFF_PHIST);
    unsigned* thresh           = (unsigned*)(ws + OFF_CNT);
    unsigned* cnt2             = thresh + 8;
    unsigned long long* seg    = (unsigned long long*)(ws + OFF_SEG);
    unsigned* ridx             = (unsigned*)(ws + OFF_RIDX);
    unsigned long long* mask   = (unsigned long long*)(ws + OFF_MASK);

    hipMemsetAsync(ws + OFF_CNT, 0, 512, stream);

    int total = B_NUM * N_ANCH;
    int blk = 256;
    k_decode<<<(total + blk - 1) / blk, blk, 0, stream>>>(
        scores, deltas, im_info, anchors, keys);
    k_hist_part<<<B_NUM * 4, 1024, 0, stream>>>(keys, phist);
    k_thresh2<<<B_NUM, 1024, 0, stream>>>(phist, thresh);
    k_scatter<<<(total + blk - 1) / blk, blk, 0, stream>>>(
        keys, thresh, cnt2, seg);
    k_sortrank<<<B_NUM, 1024, 0, stream>>>(seg, cnt2, ridx);
    k_decode2<<<(B_NUM * PRE_NMS + blk - 1) / blk, blk, 0, stream>>>(
        ridx, deltas, im_info, anchors, boxes);

    if (ws_size >= (size_t)OFF_MASK + MASK_BYTES) {
        k_iou_mask<<<B_NUM * GT_TILES, 256, 0, stream>>>(boxes, mask);
        k_nms_scan<<<B_NUM, 64, 0, stream>>>(mask, boxes, out);
    } else {
        k_nms_out<<<B_NUM, 1024, 0, stream>>>(boxes, out);
    }
}

// Round 20
// 255.755 us; speedup vs baseline: 1.5141x; 1.5141x over previous
//
#include <hip/hip_runtime.h>
#include <stdint.h>

#define FEAT_STRIDE_I 16
#define A_NUM 9
#define HH 128
#define WW 128
#define NPIX (HH * WW)            // 16384
#define N_ANCH (NPIX * A_NUM)     // 147456
#define B_NUM 8
#define PRE_NMS 6000
#define POST_NMS 300
#define NMS_THRESH_F 0.7f
#define MIN_SIZE_F 16.0f
#define NEG_INF_F -1e30f

#define NBS 16384                  // 14-bit bins (key>>18)
#define SWS(i) ((i) + ((i) >> 5))  // LDS swizzle
#define SEGL 8192                  // candidate segment cap (cnt ~6700 max)
#define QKEYS (N_ANCH / 4)         // 36864 keys per hist part

#define RT_TILES 94                // ceil(6000/64)
#define GT_TILES 600               // sum_R ceil((94-R)/8): 8-column groups
#define BQWORDS (RT_TILES * RT_TILES * 64)   // 565,504 qwords per batch

// ---- workspace layout (bytes) ----
#define OFF_KEYS    0u             // 8*147456*4 = 4,718,592
#define OFF_BOXES   4718592u       // 8*6000*4*4 = 768,000
#define OFF_PHIST   5486592u       // 8*4*16384*4 = 2,097,152
#define OFF_BBRO    7583744u       // 8*16384*4 = 524,288 (read-only binbase)
#define OFF_BBMUT   8108032u       // 524,288 (scatter slot counters)
#define OFF_CNT     8632320u       // thresh[8] + cnt[8] (512 B)
#define OFF_SEG     8632832u       // 8*8192*8 = 524,288
#define OFF_RIDX    9157120u       // 8*6000*4 = 192,000
#define OFF_MASK    9349120u       // 36,192,256 -> end 45,541,376
#define MASK_BYTES ((size_t)B_NUM * BQWORDS * 8)

__device__ __forceinline__ unsigned sortable_f32(float f) {
    unsigned u = __float_as_uint(f);
    return (u & 0x80000000u) ? ~u : (u | 0x80000000u);
}

// Decode one anchor's box exactly in the reference's op order.
__device__ __forceinline__ void decode_box(
    int b, int idx,
    const float* __restrict__ deltas, const float* __restrict__ im_info,
    const float* __restrict__ anchors,
    float& x1, float& y1, float& x2, float& y2, bool& valid)
{
    int a   = idx % A_NUM;
    int pix = idx / A_NUM;
    int w   = pix & (WW - 1);
    int h   = pix >> 7;

    float a0 = anchors[a * 4 + 0];
    float a1 = anchors[a * 4 + 1];
    float a2 = anchors[a * 4 + 2];
    float a3 = anchors[a * 4 + 3];

    float aw = __fadd_rn(__fsub_rn(a2, a0), 1.0f);
    float ah = __fadd_rn(__fsub_rn(a3, a1), 1.0f);
    float sx = (float)(w * FEAT_STRIDE_I);
    float sy = (float)(h * FEAT_STRIDE_I);
    float acx = __fadd_rn(__fadd_rn(sx, a0), __fmul_rn(0.5f, aw));
    float acy = __fadd_rn(__fadd_rn(sy, a1), __fmul_rn(0.5f, ah));

    size_t base = ((size_t)b * 36 + 4 * a) * NPIX + pix;
    float dx = deltas[base];
    float dy = deltas[base + NPIX];
    float dw = deltas[base + 2 * (size_t)NPIX];
    float dh = deltas[base + 3 * (size_t)NPIX];

    float pcx = __fadd_rn(__fmul_rn(dx, aw), acx);
    float pcy = __fadd_rn(__fmul_rn(dy, ah), acy);
    float pw  = __fmul_rn(expf(dw), aw);
    float ph  = __fmul_rn(expf(dh), ah);

    float hx = __fmul_rn(0.5f, pw);
    float hy = __fmul_rn(0.5f, ph);
    x1 = __fsub_rn(pcx, hx);
    y1 = __fsub_rn(pcy, hy);
    x2 = __fadd_rn(pcx, hx);
    y2 = __fadd_rn(pcy, hy);

    float im_h = im_info[b * 3 + 0];
    float im_w = im_info[b * 3 + 1];
    float sc   = im_info[b * 3 + 2];
    float wmax = __fsub_rn(im_w, 1.0f);
    float hmax = __fsub_rn(im_h, 1.0f);

    x1 = fminf(fmaxf(x1, 0.0f), wmax);
    y1 = fminf(fmaxf(y1, 0.0f), hmax);
    x2 = fminf(fmaxf(x2, 0.0f), wmax);
    y2 = fminf(fmaxf(y2, 0.0f), hmax);

    float min_sz = __fmul_rn(MIN_SIZE_F, sc);
    valid = (__fadd_rn(__fsub_rn(x2, x1), 1.0f) >= min_sz) &&
            (__fadd_rn(__fsub_rn(y2, y1), 1.0f) >= min_sz);
}

// K1: decode + masked score -> sortable key. Pure streaming, no atomics.
__global__ void k_decode(
    const float* __restrict__ scores, const float* __restrict__ deltas,
    const float* __restrict__ im_info, const float* __restrict__ anchors,
    unsigned* __restrict__ keys)
{
    int gt = blockIdx.x * blockDim.x + threadIdx.x;
    if (gt >= B_NUM * N_ANCH) return;
    int pix  = gt & (NPIX - 1);
    int rest = gt >> 14;
    int a = rest % A_NUM;
    int b = rest / A_NUM;
    int idx = pix * A_NUM + a;

    float x1, y1, x2, y2; bool valid;
    decode_box(b, idx, deltas, im_info, anchors, x1, y1, x2, y2, valid);

    float s = scores[((size_t)b * 18 + 9 + a) * NPIX + pix];
    if (!valid) s = NEG_INF_F;
    keys[gt] = sortable_f32(s);
}

// K2: partial histograms — 4 blocks per batch, each hists one quarter of
// the keys in a private LDS 16384-bin histogram (staged uint4 loads).
__global__ __launch_bounds__(1024) void k_hist_part(
    const unsigned* __restrict__ keys, unsigned* __restrict__ phist)
{
    __shared__ unsigned h[SWS(NBS - 1) + 2];   // 16896 words = 67.6 KB
    int b = blockIdx.x >> 2;
    int p = blockIdx.x & 3;
    int t = threadIdx.x;

    for (int i = t; i < SWS(NBS - 1) + 2; i += 1024) h[i] = 0u;
    __syncthreads();

    const uint4* kb4 = (const uint4*)(keys + (size_t)b * N_ANCH + p * QKEYS);
    uint4 v[9];
    #pragma unroll
    for (int k = 0; k < 9; ++k) v[k] = kb4[t + 1024 * k];
    #pragma unroll
    for (int k = 0; k < 9; ++k) {
        atomicAdd(&h[SWS(v[k].x >> 18)], 1u);
        atomicAdd(&h[SWS(v[k].y >> 18)], 1u);
        atomicAdd(&h[SWS(v[k].z >> 18)], 1u);
        atomicAdd(&h[SWS(v[k].w >> 18)], 1u);
    }
    __syncthreads();

    unsigned* ph = phist + (size_t)blockIdx.x * NBS;
    for (int i = t; i < NBS; i += 1024) ph[i] = h[SWS(i)];
}

// K3: per batch — sum 4 partials, suffix-scan 16384 bins, find threshold T.
// Writes TWO binbase copies (read-only for rank, mutable for scatter slot
// allocation — rewritten every call, so no memset needed), plus thresh/cnt.
__global__ __launch_bounds__(1024) void k_thresh2(
    const unsigned* __restrict__ phist, unsigned* __restrict__ bbro,
    unsigned* __restrict__ bbmut, unsigned* __restrict__ thresh,
    unsigned* __restrict__ cnt)
{
    __shared__ unsigned h[SWS(NBS - 1) + 2];
    __shared__ unsigned csum[1024];
    __shared__ unsigned sT;

    int b = blockIdx.x;
    int t = threadIdx.x;
    if (t == 0) sT = 0;

    const unsigned* ph = phist + (size_t)b * 4 * NBS;
    for (int i = t; i < NBS; i += 1024) {
        unsigned s0 = ph[i];
        unsigned s1 = ph[NBS + i];
        unsigned s2 = ph[2 * NBS + i];
        unsigned s3 = ph[3 * NBS + i];
        h[SWS(i)] = s0 + s1 + s2 + s3;
    }
    __syncthreads();

    // chunk sums (16 bins/thread) + inclusive suffix scan
    int base = t * 16;
    unsigned s = 0;
    for (int u = 0; u < 16; ++u) s += h[SWS(base + u)];
    csum[t] = s;
    __syncthreads();
    for (int off = 1; off < 1024; off <<= 1) {
        unsigned v = (t + off < 1024) ? csum[t + off] : 0u;
        __syncthreads();
        csum[t] += v;
        __syncthreads();
    }
    unsigned before = csum[t] - s;

    unsigned acc = before;
    for (int bin = base + 15; bin >= base; --bin) {
        unsigned hh = h[SWS(bin)];
        if (acc + hh >= PRE_NMS) { atomicMax(&sT, (unsigned)bin); break; }
        acc += hh;
    }
    __syncthreads();
    unsigned T = sT;

    // walk chunk high->low: overwrite LDS hist with binbase; catch cnt at T
    acc = before;
    for (int bin = base + 15; bin >= base; --bin) {
        unsigned hh = h[SWS(bin)];
        if ((unsigned)bin == T) cnt[b] = acc + hh;
        h[SWS(bin)] = acc;
        acc += hh;
    }
    if (t == 0) thresh[b] = T;
    __syncthreads();

    unsigned* r = bbro + (size_t)b * NBS;
    unsigned* m = bbmut + (size_t)b * NBS;
    for (int i = t; i < NBS; i += 1024) {
        unsigned v = h[SWS(i)];
        r[i] = v;
        m[i] = v;
    }
}

// K4: bin-segmented scatter — slot allocated by atomicAdd directly on the
// mutable binbase copy, giving the absolute position in seg. Hot-bin
// (threshold bin, ~700 same-address atomics) serializes ~10us worst case,
// parallel across the 8 batches' distinct hot addresses.
__global__ void k_scatter(
    const unsigned* __restrict__ keys, const unsigned* __restrict__ thresh,
    unsigned* __restrict__ bbmut, unsigned long long* __restrict__ seg)
{
    int gt = blockIdx.x * blockDim.x + threadIdx.x;
    int pix  = gt & (NPIX - 1);
    int rest = gt >> 14;
    int a = rest % A_NUM;
    int b = rest / A_NUM;

    unsigned key = keys[gt];
    unsigned bin = key >> 18;
    if (bin >= thresh[b]) {
        unsigned pos = atomicAdd(&bbmut[(size_t)b * NBS + bin], 1u);
        if (pos < SEGL) {
            unsigned idx = (unsigned)(pix * A_NUM + a);
            seg[(size_t)b * SEGL + pos] =
                ((unsigned long long)key << 32) | (unsigned long long)(0xFFFFFFFFu - idx);
        }
    }
}

// K5a: many-block counting rank. 32 blocks x 256 threads per batch (all
// CUs, vs the 1-block-per-batch variants that all measured 90-130us on a
// single CU). Each candidate scans only ITS bin's segment in L2-resident
// seg with an 8-wide unrolled independent-load loop; threshold bin ~700
// entries = ~88 unrolled iterations; all other bins are 1-3 entries.
// rank = binbase[bin] + #greater-in-bin is a bijection onto [0, cnt).
__global__ __launch_bounds__(256) void k_rank(
    const unsigned long long* __restrict__ seg, const unsigned* __restrict__ cnt,
    const unsigned* __restrict__ bbro, unsigned* __restrict__ ridx)
{
    int b = blockIdx.x >> 5;
    int p = ((blockIdx.x & 31) << 8) + threadIdx.x;
    unsigned n = cnt[b];
    if (n > SEGL) n = SEGL;
    if (p >= (int)n) return;

    const unsigned long long* S = seg + (size_t)b * SEGL;
    unsigned long long key = S[p];
    unsigned bin = (unsigned)(key >> 50);
    const unsigned* bb = bbro + (size_t)b * NBS;
    unsigned base = bb[bin];
    unsigned end = (bin > 0) ? bb[bin - 1] : n;   // bb[bin-1]=bb[bin]+hist[bin]
    if (end > n) end = n;

    unsigned rank = base;
    unsigned q = base;
    for (; q + 8 <= end; q += 8) {
        unsigned long long v0 = S[q + 0], v1 = S[q + 1];
        unsigned long long v2 = S[q + 2], v3 = S[q + 3];
        unsigned long long v4 = S[q + 4], v5 = S[q + 5];
        unsigned long long v6 = S[q + 6], v7 = S[q + 7];
        rank += (unsigned)(v0 > key) + (unsigned)(v1 > key)
              + (unsigned)(v2 > key) + (unsigned)(v3 > key)
              + (unsigned)(v4 > key) + (unsigned)(v5 > key)
              + (unsigned)(v6 > key) + (unsigned)(v7 > key);
    }
    for (; q < end; ++q) rank += (unsigned)(S[q] > key);

    if (rank < PRE_NMS)
        ridx[(size_t)b * PRE_NMS + rank] = 0xFFFFFFFFu - (unsigned)(key & 0xFFFFFFFFull);
}

// K5b: decode one box per output rank — 48K threads across all CUs so the
// 4-line scattered deltas gather (~12 MB of 64B lines) is latency-hidden.
__global__ void k_decode2(
    const unsigned* __restrict__ ridx,
    const float* __restrict__ deltas, const float* __restrict__ im_info,
    const float* __restrict__ anchors, float* __restrict__ boxes)
{
    int gt = blockIdx.x * blockDim.x + threadIdx.x;
    if (gt >= B_NUM * PRE_NMS) return;
    int b = gt / PRE_NMS;
    int idx = (int)ridx[gt];
    float x1, y1, x2, y2; bool v;
    decode_box(b, idx, deltas, im_info, anchors, x1, y1, x2, y2, v);
    *(float4*)(boxes + (size_t)gt * 4) = make_float4(x1, y1, x2, y2);
}

// One row of a 64x64 suppression block: inter/uni in the reference's exact
// op order; division eliminated except in the proven +-6e-7*uni band
// (round-6 proof; validated absmax=0). Returns the 64-bit suppress mask.
__device__ __forceinline__ unsigned long long iou_row(
    float4 bi, float ia, float jx1, float jy1, float jx2, float jy2, float ja)
{
    float xx1 = fmaxf(bi.x, jx1);
    float yy1 = fmaxf(bi.y, jy1);
    float xx2 = fminf(bi.z, jx2);
    float yy2 = fminf(bi.w, jy2);
    float iw = fmaxf(0.0f, __fadd_rn(__fsub_rn(xx2, xx1), 1.0f));
    float ih = fmaxf(0.0f, __fadd_rn(__fsub_rn(yy2, yy1), 1.0f));
    float inter = __fmul_rn(iw, ih);
    float uni = __fsub_rn(__fadd_rn(ia, ja), inter);
    float diff = __fsub_rn(inter, __fmul_rn(NMS_THRESH_F, uni));
    unsigned long long sup = __ballot(diff > 0.0f);
    unsigned long long band = __ballot(fabsf(diff) <= __fmul_rn(6e-7f, uni));
    if (band) {   // rare; wave-uniform branch
        unsigned long long supd = __ballot(__fdiv_rn(inter, uni) > NMS_THRESH_F);
        sup = (sup & ~band) | (supd & band);
    }
    return sup;
}

// K6: upper-triangular IoU suppression bitmask, blocked layout
// mask[b][R][C][64] (u64). 256-thread blocks: 4 waves share one row tile
// (LDS loaded once); each wave owns one column PAIR of an 8-column group.
__global__ __launch_bounds__(256) void k_iou_mask(
    const float* __restrict__ boxes, unsigned long long* __restrict__ mask)
{
    int bid = blockIdx.x;
    int b = bid / GT_TILES;
    int g = bid - b * GT_TILES;
    int R = 0;
    while (g >= ((RT_TILES - R + 7) >> 3)) { g -= (RT_TILES - R + 7) >> 3; ++R; }

    int wave = threadIdx.x >> 6;
    int lane = threadIdx.x & 63;
    const float* Bb = boxes + (size_t)b * PRE_NMS * 4;

    __shared__ float4 rb4[64];
    __shared__ float rba[64];
    if (threadIdx.x < 64) {
        int il = R * 64 + threadIdx.x;
        float4 rv = make_float4(0.f, 0.f, -1.f, -1.f);
        if (il < PRE_NMS) rv = *(const float4*)(Bb + 4 * (size_t)il);
        rb4[threadIdx.x] = rv;
        rba[threadIdx.x] = __fmul_rn(__fadd_rn(__fsub_rn(rv.z, rv.x), 1.0f),
                                     __fadd_rn(__fsub_rn(rv.w, rv.y), 1.0f));
    }
    __syncthreads();

    int C1 = R + g * 8 + wave * 2;
    int C2 = C1 + 1;
    if (C1 >= RT_TILES) return;   // tail waves idle (no barriers below)

    float j1x1 = 0.f, j1y1 = 0.f, j1x2 = -1.f, j1y2 = -1.f;
    float j2x1 = 0.f, j2y1 = 0.f, j2x2 = -1.f, j2y2 = -1.f;
    int j1 = C1 * 64 + lane;
    int j2 = C2 * 64 + lane;
    if (j1 < PRE_NMS) {
        float4 v = *(const float4*)(Bb + 4 * (size_t)j1);
        j1x1 = v.x; j1y1 = v.y; j1x2 = v.z; j1y2 = v.w;
    }
    if (C2 < RT_TILES && j2 < PRE_NMS) {
        float4 v = *(const float4*)(Bb + 4 * (size_t)j2);
        j2x1 = v.x; j2y1 = v.y; j2x2 = v.z; j2y2 = v.w;
    }
    float j1a = __fmul_rn(__fadd_rn(__fsub_rn(j1x2, j1x1), 1.0f),
                          __fadd_rn(__fsub_rn(j1y2, j1y1), 1.0f));
    float j2a = __fmul_rn(__fadd_rn(__fsub_rn(j2x2, j2x1), 1.0f),
                          __fadd_rn(__fsub_rn(j2y2, j2y1), 1.0f));

    unsigned long long w1 = 0ULL, w2 = 0ULL;
    if (C1 == R) {   // diagonal tile (g==0, wave==0 only)
        #pragma unroll 4
        for (int ri = 0; ri < 64; ++ri) {
            float4 bi = rb4[ri];
            float ia = rba[ri];
            unsigned long long s1 = iou_row(bi, ia, j1x1, j1y1, j1x2, j1y2, j1a)
                                    & (0xFFFFFFFFFFFFFFFEull << ri);
            unsigned long long s2 = iou_row(bi, ia, j2x1, j2y1, j2x2, j2y2, j2a);
            w1 = (lane == ri) ? s1 : w1;
            w2 = (lane == ri) ? s2 : w2;
        }
    } else {
        #pragma unroll 4
        for (int ri = 0; ri < 64; ++ri) {
            float4 bi = rb4[ri];
            float ia = rba[ri];
            unsigned long long s1 = iou_row(bi, ia, j1x1, j1y1, j1x2, j1y2, j1a);
            unsigned long long s2 = iou_row(bi, ia, j2x1, j2y1, j2x2, j2y2, j2a);
            w1 = (lane == ri) ? s1 : w1;
            w2 = (lane == ri) ? s2 : w2;
        }
    }

    unsigned long long* Mb = mask + (size_t)b * BQWORDS;
    Mb[(size_t)(R * RT_TILES + C1) * 64 + lane] = w1;
    if (C2 < RT_TILES)
        Mb[(size_t)(R * RT_TILES + C2) * 64 + lane] = w2;
}

// K7: serial greedy scan + fused output write. One wave per batch.
// 16-deep unconditional prefetch (static register slots); C<R(i) words
// skipped (exec-masked; zeros replace harmless garbage).
__global__ __launch_bounds__(64) void k_nms_scan(
    const unsigned long long* __restrict__ mask,
    const float* __restrict__ boxes, float* __restrict__ out)
{
    const int b = blockIdx.x;
    const int l = threadIdx.x;
    __shared__ unsigned long long supp[RT_TILES];
    __shared__ int klist[POST_NMS];
    supp[l] = 0ULL;
    if (l < RT_TILES - 64) supp[l + 64] = 0ULL;
    __syncthreads();

    const unsigned long long* __restrict__ M = mask + (size_t)b * BQWORDS;
    int kept = 0;
    unsigned long long curw = 0; int curwi = -1;

#define LOADROW(p0, p1, i) { \
        int _i = ((i) < PRE_NMS) ? (i) : (PRE_NMS - 1); \
        int _R = _i >> 6; \
        const unsigned long long* _r = M + (size_t)(_R * RT_TILES) * 64 + (_i & 63); \
        p0 = 0ULL; p1 = 0ULL; \
        if (l >= _R) p0 = _r[l * 64]; \
        if (l < RT_TILES - 64 && 64 + l >= _R) p1 = _r[(64 + l) * 64]; }

#define STEP(i, p0, p1) { \
        if (kept < POST_NMS) { \
            int _wi = (i) >> 6; \
            if (_wi != curwi) { curw = supp[_wi]; curwi = _wi; } \
            if (!((curw >> ((i) & 63)) & 1ULL)) { \
                if (l == 0) klist[kept] = (i); \
                supp[l] |= p0; \
                if (l < RT_TILES - 64) supp[l + 64] |= p1; \
                ++kept; curwi = -1; \
            } \
        } }

    unsigned long long p[16][2];
    #pragma unroll
    for (int k = 0; k < 16; ++k) { LOADROW(p[k][0], p[k][1], k) }

    for (int i = 0; i < PRE_NMS && kept < POST_NMS; i += 16) {
        #pragma unroll
        for (int k = 0; k < 16; ++k) {
            STEP(i + k, p[k][0], p[k][1])
            LOADROW(p[k][0], p[k][1], i + 16 + k)
        }
    }
    __syncthreads();

    for (int k = l; k < POST_NMS; k += 64) {
        size_t o = ((size_t)b * POST_NMS + k) * 5;
        float x1 = 0.f, y1 = 0.f, x2 = 0.f, y2 = 0.f;
        if (k < kept) {
            int idx = klist[k];
            const float4 v = *(const float4*)(boxes + ((size_t)b * PRE_NMS + idx) * 4);
            x1 = v.x; y1 = v.y; x2 = v.z; y2 = v.w;
        }
        out[o + 0] = (float)b;
        out[o + 1] = x1; out[o + 2] = y1; out[o + 3] = x2; out[o + 4] = y2;
    }
#undef LOADROW
#undef STEP
}

// Fallback NMS (used only if ws_size is too small for the bitmask).
__global__ __launch_bounds__(1024) void k_nms_out(
    const float* __restrict__ boxes, float* __restrict__ out)
{
    __shared__ float bx1[PRE_NMS], by1[PRE_NMS], bx2[PRE_NMS], by2[PRE_NMS], bar[PRE_NMS];
    __shared__ unsigned rem[(PRE_NMS + 31) / 32];
    __shared__ int kept_idx[POST_NMS];

    int b = blockIdx.x;
    int t = threadIdx.x;

    for (int p = t; p < PRE_NMS; p += 1024) {
        size_t o = ((size_t)b * PRE_NMS + p) * 4;
        float x1 = boxes[o], y1 = boxes[o + 1], x2 = boxes[o + 2], y2 = boxes[o + 3];
        bx1[p] = x1; by1[p] = y1; bx2[p] = x2; by2[p] = y2;
        bar[p] = __fmul_rn(__fadd_rn(__fsub_rn(x2, x1), 1.0f),
                           __fadd_rn(__fsub_rn(y2, y1), 1.0f));
    }
    for (int p = t; p < (PRE_NMS + 31) / 32; p += 1024) rem[p] = 0u;
    __syncthreads();

    int kept = 0;
    for (int i = 0; i < PRE_NMS && kept < POST_NMS; ++i) {
        if (rem[i >> 5] & (1u << (i & 31))) continue;
        if (t == 0) kept_idx[kept] = i;
        float xi1 = bx1[i], yi1 = by1[i], xi2 = bx2[i], yi2 = by2[i], ai = bar[i];
        for (int j = i + 1 + t; j < PRE_NMS; j += 1024) {
            float xx1 = fmaxf(xi1, bx1[j]);
            float yy1 = fmaxf(yi1, by1[j]);
            float xx2 = fminf(xi2, bx2[j]);
            float yy2 = fminf(yi2, by2[j]);
            float iw = fmaxf(0.0f, __fadd_rn(__fsub_rn(xx2, xx1), 1.0f));
            float ih = fmaxf(0.0f, __fadd_rn(__fsub_rn(yy2, yy1), 1.0f));
            float inter = __fmul_rn(iw, ih);
            if (inter > 0.0f) {
                float uni = __fsub_rn(__fadd_rn(ai, bar[j]), inter);
                float iou = __fdiv_rn(inter, uni);
                if (iou > NMS_THRESH_F) atomicOr(&rem[j >> 5], 1u << (j & 31));
            }
        }
        ++kept;
        __syncthreads();
    }

    for (int k = t; k < POST_NMS; k += 1024) {
        size_t o = ((size_t)b * POST_NMS + k) * 5;
        out[o] = (float)b;
        if (k < kept) {
            int ii = kept_idx[k];
            out[o + 1] = bx1[ii]; out[o + 2] = by1[ii];
            out[o + 3] = bx2[ii]; out[o + 4] = by2[ii];
        } else {
            out[o + 1] = 0.0f; out[o + 2] = 0.0f; out[o + 3] = 0.0f; out[o + 4] = 0.0f;
        }
    }
}

extern "C" void kernel_launch(void* const* d_in, const int* in_sizes, int n_in,
                              void* d_out, int out_size, void* d_ws, size_t ws_size,
                              hipStream_t stream)
{
    const float* scores  = (const float*)d_in[0];
    const float* deltas  = (const float*)d_in[1];
    const float* im_info = (const float*)d_in[2];
    const float* anchors = (const float*)d_in[3];
    float* out = (float*)d_out;
    char* ws = (char*)d_ws;

    unsigned* keys             = (unsigned*)(ws + OFF_KEYS);
    float* boxes               = (float*)(ws + OFF_BOXES);
    unsigned* phist            = (unsigned*)(ws + OFF_PHIST);
    unsigned* bbro             = (unsigned*)(ws + OFF_BBRO);
    unsigned* bbmut            = (unsigned*)(ws + OFF_BBMUT);
    unsigned* thresh           = (unsigned*)(ws + OFF_CNT);
    unsigned* cnt              = thresh + 8;
    unsigned long long* seg    = (unsigned long long*)(ws + OFF_SEG);
    unsigned* ridx             = (unsigned*)(ws + OFF_RIDX);
    unsigned long long* mask   = (unsigned long long*)(ws + OFF_MASK);

    int total = B_NUM * N_ANCH;
    int blk = 256;
    k_decode<<<(total + blk - 1) / blk, blk, 0, stream>>>(
        scores, deltas, im_info, anchors, keys);
    k_hist_part<<<B_NUM * 4, 1024, 0, stream>>>(keys, phist);
    k_thresh2<<<B_NUM, 1024, 0, stream>>>(phist, bbro, bbmut, thresh, cnt);
    k_scatter<<<(total + blk - 1) / blk, blk, 0, stream>>>(
        keys, thresh, bbmut, seg);
    k_rank<<<B_NUM * 32, 256, 0, stream>>>(seg, cnt, bbro, ridx);
    k_decode2<<<(B_NUM * PRE_NMS + blk - 1) / blk, blk, 0, stream>>>(
        ridx, deltas, im_info, anchors, boxes);

    if (ws_size >= (size_t)OFF_MASK + MASK_BYTES) {
        k_iou_mask<<<B_NUM * GT_TILES, 256, 0, stream>>>(boxes, mask);
        k_nms_scan<<<B_NUM, 64, 0, stream>>>(mask, boxes, out);
    } else {
        k_nms_out<<<B_NUM, 1024, 0, stream>>>(boxes, out);
    }
}

// Round 21
// 218.845 us; speedup vs baseline: 1.7694x; 1.1687x over previous
//
#include <hip/hip_runtime.h>
#include <stdint.h>

#define FEAT_STRIDE_I 16
#define A_NUM 9
#define HH 128
#define WW 128
#define NPIX (HH * WW)            // 16384
#define N_ANCH (NPIX * A_NUM)     // 147456
#define B_NUM 8
#define PRE_NMS 6000
#define POST_NMS 300
#define NMS_THRESH_F 0.7f
#define MIN_SIZE_F 16.0f
#define NEG_INF_F -1e30f

#define NBS 16384                  // 14-bit bins (key>>18)
#define SWS(i) ((i) + ((i) >> 5))  // LDS swizzle
#define SEGL 8192                  // candidate segment cap (cnt ~6700 max)
#define QKEYS (N_ANCH / 4)         // 36864 keys per hist part

#define RT_TILES 94                // ceil(6000/64)
#define GT_TILES 600               // sum_R ceil((94-R)/8): 8-column groups
#define BQWORDS (RT_TILES * RT_TILES * 64)   // 565,504 qwords per batch

// truncated-IoU split: phase A computes row-tiles R < R_SPLIT (rows 0..1023);
// the tail (R >= R_SPLIT) is skipped per batch when the scan already kept 300.
#define R_SPLIT 16
#define ROWS_SPLIT (R_SPLIT * 64)  // 1024
#define G_HEAD 180                 // sum_{R=0..15} (101-R)>>3
#define G_TAIL (GT_TILES - G_HEAD) // 420
#define STATE_STRIDE 2048          // per-batch scan state (kept,done,supp,klist)

// ---- workspace layout (bytes) ----
#define OFF_KEYS    0u             // 8*147456*4 = 4,718,592
#define OFF_BOXES   4718592u       // 8*6000*4*4 = 768,000
#define OFF_PHIST   5486592u       // 8*4*16384*4 = 2,097,152
#define OFF_BBRO    7583744u       // 8*16384*4 = 524,288 (read-only binbase)
#define OFF_BBMUT   8108032u       // 524,288 (scatter slot counters)
#define OFF_CNT     8632320u       // thresh[8] + cnt[8] (512 B)
#define OFF_SEG     8632832u       // 8*8192*8 = 524,288
#define OFF_RIDX    9157120u       // 8*6000*4 = 192,000
#define OFF_STATE   9349120u       // 8*2048 = 16,384
#define OFF_MASK    9365504u       // 36,192,256 -> end 45,557,760
#define MASK_BYTES ((size_t)B_NUM * BQWORDS * 8)

__device__ __forceinline__ unsigned sortable_f32(float f) {
    unsigned u = __float_as_uint(f);
    return (u & 0x80000000u) ? ~u : (u | 0x80000000u);
}

// Decode one anchor's box exactly in the reference's op order.
__device__ __forceinline__ void decode_box(
    int b, int idx,
    const float* __restrict__ deltas, const float* __restrict__ im_info,
    const float* __restrict__ anchors,
    float& x1, float& y1, float& x2, float& y2, bool& valid)
{
    int a   = idx % A_NUM;
    int pix = idx / A_NUM;
    int w   = pix & (WW - 1);
    int h   = pix >> 7;

    float a0 = anchors[a * 4 + 0];
    float a1 = anchors[a * 4 + 1];
    float a2 = anchors[a * 4 + 2];
    float a3 = anchors[a * 4 + 3];

    float aw = __fadd_rn(__fsub_rn(a2, a0), 1.0f);
    float ah = __fadd_rn(__fsub_rn(a3, a1), 1.0f);
    float sx = (float)(w * FEAT_STRIDE_I);
    float sy = (float)(h * FEAT_STRIDE_I);
    float acx = __fadd_rn(__fadd_rn(sx, a0), __fmul_rn(0.5f, aw));
    float acy = __fadd_rn(__fadd_rn(sy, a1), __fmul_rn(0.5f, ah));

    size_t base = ((size_t)b * 36 + 4 * a) * NPIX + pix;
    float dx = deltas[base];
    float dy = deltas[base + NPIX];
    float dw = deltas[base + 2 * (size_t)NPIX];
    float dh = deltas[base + 3 * (size_t)NPIX];

    float pcx = __fadd_rn(__fmul_rn(dx, aw), acx);
    float pcy = __fadd_rn(__fmul_rn(dy, ah), acy);
    float pw  = __fmul_rn(expf(dw), aw);
    float ph  = __fmul_rn(expf(dh), ah);

    float hx = __fmul_rn(0.5f, pw);
    float hy = __fmul_rn(0.5f, ph);
    x1 = __fsub_rn(pcx, hx);
    y1 = __fsub_rn(pcy, hy);
    x2 = __fadd_rn(pcx, hx);
    y2 = __fadd_rn(pcy, hy);

    float im_h = im_info[b * 3 + 0];
    float im_w = im_info[b * 3 + 1];
    float sc   = im_info[b * 3 + 2];
    float wmax = __fsub_rn(im_w, 1.0f);
    float hmax = __fsub_rn(im_h, 1.0f);

    x1 = fminf(fmaxf(x1, 0.0f), wmax);
    y1 = fminf(fmaxf(y1, 0.0f), hmax);
    x2 = fminf(fmaxf(x2, 0.0f), wmax);
    y2 = fminf(fmaxf(y2, 0.0f), hmax);

    float min_sz = __fmul_rn(MIN_SIZE_F, sc);
    valid = (__fadd_rn(__fsub_rn(x2, x1), 1.0f) >= min_sz) &&
            (__fadd_rn(__fsub_rn(y2, y1), 1.0f) >= min_sz);
}

// K1: decode + masked score -> sortable key. Pure streaming, no atomics.
__global__ void k_decode(
    const float* __restrict__ scores, const float* __restrict__ deltas,
    const float* __restrict__ im_info, const float* __restrict__ anchors,
    unsigned* __restrict__ keys)
{
    int gt = blockIdx.x * blockDim.x + threadIdx.x;
    if (gt >= B_NUM * N_ANCH) return;
    int pix  = gt & (NPIX - 1);
    int rest = gt >> 14;
    int a = rest % A_NUM;
    int b = rest / A_NUM;
    int idx = pix * A_NUM + a;

    float x1, y1, x2, y2; bool valid;
    decode_box(b, idx, deltas, im_info, anchors, x1, y1, x2, y2, valid);

    float s = scores[((size_t)b * 18 + 9 + a) * NPIX + pix];
    if (!valid) s = NEG_INF_F;
    keys[gt] = sortable_f32(s);
}

// K2: partial histograms — 4 blocks per batch, each hists one quarter of
// the keys in a private LDS 16384-bin histogram (staged uint4 loads).
__global__ __launch_bounds__(1024) void k_hist_part(
    const unsigned* __restrict__ keys, unsigned* __restrict__ phist)
{
    __shared__ unsigned h[SWS(NBS - 1) + 2];   // 16896 words = 67.6 KB
    int b = blockIdx.x >> 2;
    int p = blockIdx.x & 3;
    int t = threadIdx.x;

    for (int i = t; i < SWS(NBS - 1) + 2; i += 1024) h[i] = 0u;
    __syncthreads();

    const uint4* kb4 = (const uint4*)(keys + (size_t)b * N_ANCH + p * QKEYS);
    uint4 v[9];
    #pragma unroll
    for (int k = 0; k < 9; ++k) v[k] = kb4[t + 1024 * k];
    #pragma unroll
    for (int k = 0; k < 9; ++k) {
        atomicAdd(&h[SWS(v[k].x >> 18)], 1u);
        atomicAdd(&h[SWS(v[k].y >> 18)], 1u);
        atomicAdd(&h[SWS(v[k].z >> 18)], 1u);
        atomicAdd(&h[SWS(v[k].w >> 18)], 1u);
    }
    __syncthreads();

    unsigned* ph = phist + (size_t)blockIdx.x * NBS;
    for (int i = t; i < NBS; i += 1024) ph[i] = h[SWS(i)];
}

// K3: per batch — sum 4 partials, suffix-scan 16384 bins, find threshold T.
// Writes TWO binbase copies (read-only for rank, mutable for scatter slot
// allocation — rewritten every call, so no memset needed), plus thresh/cnt.
__global__ __launch_bounds__(1024) void k_thresh2(
    const unsigned* __restrict__ phist, unsigned* __restrict__ bbro,
    unsigned* __restrict__ bbmut, unsigned* __restrict__ thresh,
    unsigned* __restrict__ cnt)
{
    __shared__ unsigned h[SWS(NBS - 1) + 2];
    __shared__ unsigned csum[1024];
    __shared__ unsigned sT;

    int b = blockIdx.x;
    int t = threadIdx.x;
    if (t == 0) sT = 0;

    const unsigned* ph = phist + (size_t)b * 4 * NBS;
    for (int i = t; i < NBS; i += 1024) {
        unsigned s0 = ph[i];
        unsigned s1 = ph[NBS + i];
        unsigned s2 = ph[2 * NBS + i];
        unsigned s3 = ph[3 * NBS + i];
        h[SWS(i)] = s0 + s1 + s2 + s3;
    }
    __syncthreads();

    int base = t * 16;
    unsigned s = 0;
    for (int u = 0; u < 16; ++u) s += h[SWS(base + u)];
    csum[t] = s;
    __syncthreads();
    for (int off = 1; off < 1024; off <<= 1) {
        unsigned v = (t + off < 1024) ? csum[t + off] : 0u;
        __syncthreads();
        csum[t] += v;
        __syncthreads();
    }
    unsigned before = csum[t] - s;

    unsigned acc = before;
    for (int bin = base + 15; bin >= base; --bin) {
        unsigned hh = h[SWS(bin)];
        if (acc + hh >= PRE_NMS) { atomicMax(&sT, (unsigned)bin); break; }
        acc += hh;
    }
    __syncthreads();
    unsigned T = sT;

    acc = before;
    for (int bin = base + 15; bin >= base; --bin) {
        unsigned hh = h[SWS(bin)];
        if ((unsigned)bin == T) cnt[b] = acc + hh;
        h[SWS(bin)] = acc;
        acc += hh;
    }
    if (t == 0) thresh[b] = T;
    __syncthreads();

    unsigned* r = bbro + (size_t)b * NBS;
    unsigned* m = bbmut + (size_t)b * NBS;
    for (int i = t; i < NBS; i += 1024) {
        unsigned v = h[SWS(i)];
        r[i] = v;
        m[i] = v;
    }
}

// K4: bin-segmented scatter — slot allocated by atomicAdd on the mutable
// binbase copy, giving the absolute position in seg.
__global__ void k_scatter(
    const unsigned* __restrict__ keys, const unsigned* __restrict__ thresh,
    unsigned* __restrict__ bbmut, unsigned long long* __restrict__ seg)
{
    int gt = blockIdx.x * blockDim.x + threadIdx.x;
    int pix  = gt & (NPIX - 1);
    int rest = gt >> 14;
    int a = rest % A_NUM;
    int b = rest / A_NUM;

    unsigned key = keys[gt];
    unsigned bin = key >> 18;
    if (bin >= thresh[b]) {
        unsigned pos = atomicAdd(&bbmut[(size_t)b * NBS + bin], 1u);
        if (pos < SEGL) {
            unsigned idx = (unsigned)(pix * A_NUM + a);
            seg[(size_t)b * SEGL + pos] =
                ((unsigned long long)key << 32) | (unsigned long long)(0xFFFFFFFFu - idx);
        }
    }
}

// K5a: many-block counting rank (32 blocks x 256 thr per batch, all CUs).
__global__ __launch_bounds__(256) void k_rank(
    const unsigned long long* __restrict__ seg, const unsigned* __restrict__ cnt,
    const unsigned* __restrict__ bbro, unsigned* __restrict__ ridx)
{
    int b = blockIdx.x >> 5;
    int p = ((blockIdx.x & 31) << 8) + threadIdx.x;
    unsigned n = cnt[b];
    if (n > SEGL) n = SEGL;
    if (p >= (int)n) return;

    const unsigned long long* S = seg + (size_t)b * SEGL;
    unsigned long long key = S[p];
    unsigned bin = (unsigned)(key >> 50);
    const unsigned* bb = bbro + (size_t)b * NBS;
    unsigned base = bb[bin];
    unsigned end = (bin > 0) ? bb[bin - 1] : n;
    if (end > n) end = n;

    unsigned rank = base;
    unsigned q = base;
    for (; q + 8 <= end; q += 8) {
        unsigned long long v0 = S[q + 0], v1 = S[q + 1];
        unsigned long long v2 = S[q + 2], v3 = S[q + 3];
        unsigned long long v4 = S[q + 4], v5 = S[q + 5];
        unsigned long long v6 = S[q + 6], v7 = S[q + 7];
        rank += (unsigned)(v0 > key) + (unsigned)(v1 > key)
              + (unsigned)(v2 > key) + (unsigned)(v3 > key)
              + (unsigned)(v4 > key) + (unsigned)(v5 > key)
              + (unsigned)(v6 > key) + (unsigned)(v7 > key);
    }
    for (; q < end; ++q) rank += (unsigned)(S[q] > key);

    if (rank < PRE_NMS)
        ridx[(size_t)b * PRE_NMS + rank] = 0xFFFFFFFFu - (unsigned)(key & 0xFFFFFFFFull);
}

// K5b: decode one box per output rank across all CUs.
__global__ void k_decode2(
    const unsigned* __restrict__ ridx,
    const float* __restrict__ deltas, const float* __restrict__ im_info,
    const float* __restrict__ anchors, float* __restrict__ boxes)
{
    int gt = blockIdx.x * blockDim.x + threadIdx.x;
    if (gt >= B_NUM * PRE_NMS) return;
    int b = gt / PRE_NMS;
    int idx = (int)ridx[gt];
    float x1, y1, x2, y2; bool v;
    decode_box(b, idx, deltas, im_info, anchors, x1, y1, x2, y2, v);
    *(float4*)(boxes + (size_t)gt * 4) = make_float4(x1, y1, x2, y2);
}

// One row of a 64x64 suppression block (exact ref op order; div only in the
// proven +-6e-7*uni band — validated absmax=0 since round 6).
__device__ __forceinline__ unsigned long long iou_row(
    float4 bi, float ia, float jx1, float jy1, float jx2, float jy2, float ja)
{
    float xx1 = fmaxf(bi.x, jx1);
    float yy1 = fmaxf(bi.y, jy1);
    float xx2 = fminf(bi.z, jx2);
    float yy2 = fminf(bi.w, jy2);
    float iw = fmaxf(0.0f, __fadd_rn(__fsub_rn(xx2, xx1), 1.0f));
    float ih = fmaxf(0.0f, __fadd_rn(__fsub_rn(yy2, yy1), 1.0f));
    float inter = __fmul_rn(iw, ih);
    float uni = __fsub_rn(__fadd_rn(ia, ja), inter);
    float diff = __fsub_rn(inter, __fmul_rn(NMS_THRESH_F, uni));
    unsigned long long sup = __ballot(diff > 0.0f);
    unsigned long long band = __ballot(fabsf(diff) <= __fmul_rn(6e-7f, uni));
    if (band) {
        unsigned long long supd = __ballot(__fdiv_rn(inter, uni) > NMS_THRESH_F);
        sup = (sup & ~band) | (supd & band);
    }
    return sup;
}

// K6: IoU suppression bitmask for row-tiles R in [Rstart, ...), ngroups
// 8-column groups per batch. statep!=null: skip batch if its scan already
// finished (done flag) — the truncated-IoU tail. Layout mask[b][R][C][64].
__global__ __launch_bounds__(256) void k_iou_mask(
    const float* __restrict__ boxes, unsigned long long* __restrict__ mask,
    int Rstart, int ngroups, const char* __restrict__ statep)
{
    int bid = blockIdx.x;
    int b = bid / ngroups;
    int g = bid - b * ngroups;
    if (statep && ((const int*)(statep + (size_t)b * STATE_STRIDE))[1]) return;

    int R = Rstart;
    while (g >= ((RT_TILES - R + 7) >> 3)) { g -= (RT_TILES - R + 7) >> 3; ++R; }

    int wave = threadIdx.x >> 6;
    int lane = threadIdx.x & 63;
    const float* Bb = boxes + (size_t)b * PRE_NMS * 4;

    __shared__ float4 rb4[64];
    __shared__ float rba[64];
    if (threadIdx.x < 64) {
        int il = R * 64 + threadIdx.x;
        float4 rv = make_float4(0.f, 0.f, -1.f, -1.f);
        if (il < PRE_NMS) rv = *(const float4*)(Bb + 4 * (size_t)il);
        rb4[threadIdx.x] = rv;
        rba[threadIdx.x] = __fmul_rn(__fadd_rn(__fsub_rn(rv.z, rv.x), 1.0f),
                                     __fadd_rn(__fsub_rn(rv.w, rv.y), 1.0f));
    }
    __syncthreads();

    int C1 = R + g * 8 + wave * 2;
    int C2 = C1 + 1;
    if (C1 >= RT_TILES) return;   // tail waves idle (no barriers below)

    float j1x1 = 0.f, j1y1 = 0.f, j1x2 = -1.f, j1y2 = -1.f;
    float j2x1 = 0.f, j2y1 = 0.f, j2x2 = -1.f, j2y2 = -1.f;
    int j1 = C1 * 64 + lane;
    int j2 = C2 * 64 + lane;
    if (j1 < PRE_NMS) {
        float4 v = *(const float4*)(Bb + 4 * (size_t)j1);
        j1x1 = v.x; j1y1 = v.y; j1x2 = v.z; j1y2 = v.w;
    }
    if (C2 < RT_TILES && j2 < PRE_NMS) {
        float4 v = *(const float4*)(Bb + 4 * (size_t)j2);
        j2x1 = v.x; j2y1 = v.y; j2x2 = v.z; j2y2 = v.w;
    }
    float j1a = __fmul_rn(__fadd_rn(__fsub_rn(j1x2, j1x1), 1.0f),
                          __fadd_rn(__fsub_rn(j1y2, j1y1), 1.0f));
    float j2a = __fmul_rn(__fadd_rn(__fsub_rn(j2x2, j2x1), 1.0f),
                          __fadd_rn(__fsub_rn(j2y2, j2y1), 1.0f));

    unsigned long long w1 = 0ULL, w2 = 0ULL;
    if (C1 == R) {   // diagonal tile
        #pragma unroll 4
        for (int ri = 0; ri < 64; ++ri) {
            float4 bi = rb4[ri];
            float ia = rba[ri];
            unsigned long long s1 = iou_row(bi, ia, j1x1, j1y1, j1x2, j1y2, j1a)
                                    & (0xFFFFFFFFFFFFFFFEull << ri);
            unsigned long long s2 = iou_row(bi, ia, j2x1, j2y1, j2x2, j2y2, j2a);
            w1 = (lane == ri) ? s1 : w1;
            w2 = (lane == ri) ? s2 : w2;
        }
    } else {
        #pragma unroll 4
        for (int ri = 0; ri < 64; ++ri) {
            float4 bi = rb4[ri];
            float ia = rba[ri];
            unsigned long long s1 = iou_row(bi, ia, j1x1, j1y1, j1x2, j1y2, j1a);
            unsigned long long s2 = iou_row(bi, ia, j2x1, j2y1, j2x2, j2y2, j2a);
            w1 = (lane == ri) ? s1 : w1;
            w2 = (lane == ri) ? s2 : w2;
        }
    }

    unsigned long long* Mb = mask + (size_t)b * BQWORDS;
    Mb[(size_t)(R * RT_TILES + C1) * 64 + lane] = w1;
    if (C2 < RT_TILES)
        Mb[(size_t)(R * RT_TILES + C2) * 64 + lane] = w2;
}

// K7: greedy scan over rows [row_begin,row_end), resumable. One wave/batch.
// State per batch (STATE_STRIDE bytes): [0]=kept, [4]=done, supp u64[94] at
// +16, klist int[300] at +768. row_begin==0 initializes fresh; else restores.
// final_phase: write output; else save state and set done=(kept>=300).
__global__ __launch_bounds__(64) void k_nms_scan_part(
    const unsigned long long* __restrict__ mask,
    const float* __restrict__ boxes, float* __restrict__ out,
    char* __restrict__ statep, int row_begin, int row_end, int final_phase)
{
    const int b = blockIdx.x;
    const int l = threadIdx.x;
    char* st = statep + (size_t)b * STATE_STRIDE;
    int* s_meta = (int*)st;
    unsigned long long* s_supp = (unsigned long long*)(st + 16);
    int* s_klist = (int*)(st + 768);

    __shared__ unsigned long long supp[RT_TILES];
    __shared__ int klist[POST_NMS];
    int kept, done;

    if (row_begin == 0) {
        supp[l] = 0ULL;
        if (l < RT_TILES - 64) supp[l + 64] = 0ULL;
        kept = 0; done = 0;
    } else {
        kept = s_meta[0];
        done = s_meta[1];
        supp[l] = s_supp[l];
        if (l < RT_TILES - 64) supp[l + 64] = s_supp[64 + l];
        for (int k = l; k < POST_NMS; k += 64) klist[k] = s_klist[k];
    }
    __syncthreads();

    const unsigned long long* __restrict__ M = mask + (size_t)b * BQWORDS;
    unsigned long long curw = 0; int curwi = -1;

#define LOADROW(p0, p1, i) { \
        int _i = ((i) < PRE_NMS) ? (i) : (PRE_NMS - 1); \
        int _R = _i >> 6; \
        const unsigned long long* _r = M + (size_t)(_R * RT_TILES) * 64 + (_i & 63); \
        p0 = 0ULL; p1 = 0ULL; \
        if (l >= _R) p0 = _r[l * 64]; \
        if (l < RT_TILES - 64 && 64 + l >= _R) p1 = _r[(64 + l) * 64]; }

#define STEP(i, p0, p1) { \
        if (kept < POST_NMS) { \
            int _wi = (i) >> 6; \
            if (_wi != curwi) { curw = supp[_wi]; curwi = _wi; } \
            if (!((curw >> ((i) & 63)) & 1ULL)) { \
                if (l == 0) klist[kept] = (i); \
                supp[l] |= p0; \
                if (l < RT_TILES - 64) supp[l + 64] |= p1; \
                ++kept; curwi = -1; \
            } \
        } }

    if (!done && kept < POST_NMS) {
        unsigned long long p[16][2];
        #pragma unroll
        for (int k = 0; k < 16; ++k) { LOADROW(p[k][0], p[k][1], row_begin + k) }

        for (int i = row_begin; i < row_end && kept < POST_NMS; i += 16) {
            #pragma unroll
            for (int k = 0; k < 16; ++k) {
                STEP(i + k, p[k][0], p[k][1])
                LOADROW(p[k][0], p[k][1], i + 16 + k)
            }
        }
    }
    __syncthreads();

    if (!final_phase) {
        if (l == 0) { s_meta[0] = kept; s_meta[1] = (kept >= POST_NMS) ? 1 : 0; }
        s_supp[l] = supp[l];
        if (l < RT_TILES - 64) s_supp[64 + l] = supp[l + 64];
        for (int k = l; k < POST_NMS; k += 64) s_klist[k] = klist[k];
    } else {
        for (int k = l; k < POST_NMS; k += 64) {
            size_t o = ((size_t)b * POST_NMS + k) * 5;
            float x1 = 0.f, y1 = 0.f, x2 = 0.f, y2 = 0.f;
            if (k < kept) {
                int idx = klist[k];
                const float4 v = *(const float4*)(boxes + ((size_t)b * PRE_NMS + idx) * 4);
                x1 = v.x; y1 = v.y; x2 = v.z; y2 = v.w;
            }
            out[o + 0] = (float)b;
            out[o + 1] = x1; out[o + 2] = y1; out[o + 3] = x2; out[o + 4] = y2;
        }
    }
#undef LOADROW
#undef STEP
}

// Fallback NMS (used only if ws_size is too small for the bitmask).
__global__ __launch_bounds__(1024) void k_nms_out(
    const float* __restrict__ boxes, float* __restrict__ out)
{
    __shared__ float bx1[PRE_NMS], by1[PRE_NMS], bx2[PRE_NMS], by2[PRE_NMS], bar[PRE_NMS];
    __shared__ unsigned rem[(PRE_NMS + 31) / 32];
    __shared__ int kept_idx[POST_NMS];

    int b = blockIdx.x;
    int t = threadIdx.x;

    for (int p = t; p < PRE_NMS; p += 1024) {
        size_t o = ((size_t)b * PRE_NMS + p) * 4;
        float x1 = boxes[o], y1 = boxes[o + 1], x2 = boxes[o + 2], y2 = boxes[o + 3];
        bx1[p] = x1; by1[p] = y1; bx2[p] = x2; by2[p] = y2;
        bar[p] = __fmul_rn(__fadd_rn(__fsub_rn(x2, x1), 1.0f),
                           __fadd_rn(__fsub_rn(y2, y1), 1.0f));
    }
    for (int p = t; p < (PRE_NMS + 31) / 32; p += 1024) rem[p] = 0u;
    __syncthreads();

    int kept = 0;
    for (int i = 0; i < PRE_NMS && kept < POST_NMS; ++i) {
        if (rem[i >> 5] & (1u << (i & 31))) continue;
        if (t == 0) kept_idx[kept] = i;
        float xi1 = bx1[i], yi1 = by1[i], xi2 = bx2[i], yi2 = by2[i], ai = bar[i];
        for (int j = i + 1 + t; j < PRE_NMS; j += 1024) {
            float xx1 = fmaxf(xi1, bx1[j]);
            float yy1 = fmaxf(yi1, by1[j]);
            float xx2 = fminf(xi2, bx2[j]);
            float yy2 = fminf(yi2, by2[j]);
            float iw = fmaxf(0.0f, __fadd_rn(__fsub_rn(xx2, xx1), 1.0f));
            float ih = fmaxf(0.0f, __fadd_rn(__fsub_rn(yy2, yy1), 1.0f));
            float inter = __fmul_rn(iw, ih);
            if (inter > 0.0f) {
                float uni = __fsub_rn(__fadd_rn(ai, bar[j]), inter);
                float iou = __fdiv_rn(inter, uni);
                if (iou > NMS_THRESH_F) atomicOr(&rem[j >> 5], 1u << (j & 31));
            }
        }
        ++kept;
        __syncthreads();
    }

    for (int k = t; k < POST_NMS; k += 1024) {
        size_t o = ((size_t)b * POST_NMS + k) * 5;
        out[o] = (float)b;
        if (k < kept) {
            int ii = kept_idx[k];
            out[o + 1] = bx1[ii]; out[o + 2] = by1[ii];
            out[o + 3] = bx2[ii]; out[o + 4] = by2[ii];
        } else {
            out[o + 1] = 0.0f; out[o + 2] = 0.0f; out[o + 3] = 0.0f; out[o + 4] = 0.0f;
        }
    }
}

extern "C" void kernel_launch(void* const* d_in, const int* in_sizes, int n_in,
                              void* d_out, int out_size, void* d_ws, size_t ws_size,
                              hipStream_t stream)
{
    const float* scores  = (const float*)d_in[0];
    const float* deltas  = (const float*)d_in[1];
    const float* im_info = (const float*)d_in[2];
    const float* anchors = (const float*)d_in[3];
    float* out = (float*)d_out;
    char* ws = (char*)d_ws;

    unsigned* keys             = (unsigned*)(ws + OFF_KEYS);
    float* boxes               = (float*)(ws + OFF_BOXES);
    unsigned* phist            = (unsigned*)(ws + OFF_PHIST);
    unsigned* bbro             = (unsigned*)(ws + OFF_BBRO);
    unsigned* bbmut            = (unsigned*)(ws + OFF_BBMUT);
    unsigned* thresh           = (unsigned*)(ws + OFF_CNT);
    unsigned* cnt              = thresh + 8;
    unsigned long long* seg    = (unsigned long long*)(ws + OFF_SEG);
    unsigned* ridx             = (unsigned*)(ws + OFF_RIDX);
    char* state                = (char*)(ws + OFF_STATE);
    unsigned long long* mask   = (unsigned long long*)(ws + OFF_MASK);

    int total = B_NUM * N_ANCH;
    int blk = 256;
    k_decode<<<(total + blk - 1) / blk, blk, 0, stream>>>(
        scores, deltas, im_info, anchors, keys);
    k_hist_part<<<B_NUM * 4, 1024, 0, stream>>>(keys, phist);
    k_thresh2<<<B_NUM, 1024, 0, stream>>>(phist, bbro, bbmut, thresh, cnt);
    k_scatter<<<(total + blk - 1) / blk, blk, 0, stream>>>(
        keys, thresh, bbmut, seg);
    k_rank<<<B_NUM * 32, 256, 0, stream>>>(seg, cnt, bbro, ridx);
    k_decode2<<<(B_NUM * PRE_NMS + blk - 1) / blk, blk, 0, stream>>>(
        ridx, deltas, im_info, anchors, boxes);

    if (ws_size >= (size_t)OFF_MASK + MASK_BYTES) {
        // phase A: rows 0..1023 only
        k_iou_mask<<<B_NUM * G_HEAD, 256, 0, stream>>>(
            boxes, mask, 0, G_HEAD, (const char*)0);
        // scan p1: early-stop within rows < 1024; persist state + done flag
        k_nms_scan_part<<<B_NUM, 64, 0, stream>>>(
            mask, boxes, out, state, 0, ROWS_SPLIT, 0);
        // tail: rows >= 1024, skipped per batch when done
        k_iou_mask<<<B_NUM * G_TAIL, 256, 0, stream>>>(
            boxes, mask, R_SPLIT, G_TAIL, (const char*)state);
        // scan p2: finish (or just write output if already done)
        k_nms_scan_part<<<B_NUM, 64, 0, stream>>>(
            mask, boxes, out, state, ROWS_SPLIT, PRE_NMS, 1);
    } else {
        k_nms_out<<<B_NUM, 1024, 0, stream>>>(boxes, out);
    }
}

// Round 22
// 214.123 us; speedup vs baseline: 1.8085x; 1.0221x over previous
//
#include <hip/hip_runtime.h>
#include <stdint.h>

#define FEAT_STRIDE_I 16
#define A_NUM 9
#define HH 128
#define WW 128
#define NPIX (HH * WW)            // 16384
#define N_ANCH (NPIX * A_NUM)     // 147456
#define B_NUM 8
#define PRE_NMS 6000
#define POST_NMS 300
#define NMS_THRESH_F 0.7f
#define MIN_SIZE_F 16.0f
#define NEG_INF_F -1e30f

#define NBS 16384                  // 14-bit bins (key>>18)
#define SWS(i) ((i) + ((i) >> 5))  // LDS swizzle
#define SEGL 8192                  // candidate segment cap (cnt ~6700 max)
#define QKEYS (N_ANCH / 4)         // 36864 keys per hist part

#define RT_TILES 94                // ceil(6000/64)
#define GT_TILES 600               // sum_R ceil((94-R)/8): 8-column groups
#define BQWORDS (RT_TILES * RT_TILES * 64)   // 565,504 qwords per batch

// truncated-IoU split: phase A computes row-tiles R < R_SPLIT (rows 0..1023);
// the tail (R >= R_SPLIT) is skipped per batch when the scan already kept 300.
#define R_SPLIT 16
#define ROWS_SPLIT (R_SPLIT * 64)  // 1024
#define G_HEAD 180                 // sum_{R=0..15} (101-R)>>3
#define G_TAIL (GT_TILES - G_HEAD) // 420
#define STATE_STRIDE 2048          // per-batch scan state (kept,done,supp,klist)

// ---- workspace layout (bytes) ----
#define OFF_KEYS    0u             // 8*147456*4 = 4,718,592
#define OFF_BOXES   4718592u       // 8*6000*4*4 = 768,000
#define OFF_PHIST   5486592u       // 8*4*16384*4 = 2,097,152
#define OFF_BBRO    7583744u       // 8*16384*4 = 524,288 (read-only binbase)
#define OFF_BBMUT   8108032u       // 524,288 (scatter slot counters)
#define OFF_CNT     8632320u       // thresh[8] + cnt[8] (512 B)
#define OFF_SEG     8632832u       // 8*8192*8 = 524,288
#define OFF_RIDX    9157120u       // 8*6000*4 = 192,000
#define OFF_STATE   9349120u       // 8*2048 = 16,384
#define OFF_MASK    9365504u       // 36,192,256 -> end 45,557,760
#define MASK_BYTES ((size_t)B_NUM * BQWORDS * 8)

__device__ __forceinline__ unsigned sortable_f32(float f) {
    unsigned u = __float_as_uint(f);
    return (u & 0x80000000u) ? ~u : (u | 0x80000000u);
}

// Decode one anchor's box exactly in the reference's op order.
__device__ __forceinline__ void decode_box(
    int b, int idx,
    const float* __restrict__ deltas, const float* __restrict__ im_info,
    const float* __restrict__ anchors,
    float& x1, float& y1, float& x2, float& y2, bool& valid)
{
    int a   = idx % A_NUM;
    int pix = idx / A_NUM;
    int w   = pix & (WW - 1);
    int h   = pix >> 7;

    float a0 = anchors[a * 4 + 0];
    float a1 = anchors[a * 4 + 1];
    float a2 = anchors[a * 4 + 2];
    float a3 = anchors[a * 4 + 3];

    float aw = __fadd_rn(__fsub_rn(a2, a0), 1.0f);
    float ah = __fadd_rn(__fsub_rn(a3, a1), 1.0f);
    float sx = (float)(w * FEAT_STRIDE_I);
    float sy = (float)(h * FEAT_STRIDE_I);
    float acx = __fadd_rn(__fadd_rn(sx, a0), __fmul_rn(0.5f, aw));
    float acy = __fadd_rn(__fadd_rn(sy, a1), __fmul_rn(0.5f, ah));

    size_t base = ((size_t)b * 36 + 4 * a) * NPIX + pix;
    float dx = deltas[base];
    float dy = deltas[base + NPIX];
    float dw = deltas[base + 2 * (size_t)NPIX];
    float dh = deltas[base + 3 * (size_t)NPIX];

    float pcx = __fadd_rn(__fmul_rn(dx, aw), acx);
    float pcy = __fadd_rn(__fmul_rn(dy, ah), acy);
    float pw  = __fmul_rn(expf(dw), aw);
    float ph  = __fmul_rn(expf(dh), ah);

    float hx = __fmul_rn(0.5f, pw);
    float hy = __fmul_rn(0.5f, ph);
    x1 = __fsub_rn(pcx, hx);
    y1 = __fsub_rn(pcy, hy);
    x2 = __fadd_rn(pcx, hx);
    y2 = __fadd_rn(pcy, hy);

    float im_h = im_info[b * 3 + 0];
    float im_w = im_info[b * 3 + 1];
    float sc   = im_info[b * 3 + 2];
    float wmax = __fsub_rn(im_w, 1.0f);
    float hmax = __fsub_rn(im_h, 1.0f);

    x1 = fminf(fmaxf(x1, 0.0f), wmax);
    y1 = fminf(fmaxf(y1, 0.0f), hmax);
    x2 = fminf(fmaxf(x2, 0.0f), wmax);
    y2 = fminf(fmaxf(y2, 0.0f), hmax);

    float min_sz = __fmul_rn(MIN_SIZE_F, sc);
    valid = (__fadd_rn(__fsub_rn(x2, x1), 1.0f) >= min_sz) &&
            (__fadd_rn(__fsub_rn(y2, y1), 1.0f) >= min_sz);
}

// K1: decode + masked score -> sortable key. Pure streaming, no atomics.
__global__ void k_decode(
    const float* __restrict__ scores, const float* __restrict__ deltas,
    const float* __restrict__ im_info, const float* __restrict__ anchors,
    unsigned* __restrict__ keys)
{
    int gt = blockIdx.x * blockDim.x + threadIdx.x;
    if (gt >= B_NUM * N_ANCH) return;
    int pix  = gt & (NPIX - 1);
    int rest = gt >> 14;
    int a = rest % A_NUM;
    int b = rest / A_NUM;
    int idx = pix * A_NUM + a;

    float x1, y1, x2, y2; bool valid;
    decode_box(b, idx, deltas, im_info, anchors, x1, y1, x2, y2, valid);

    float s = scores[((size_t)b * 18 + 9 + a) * NPIX + pix];
    if (!valid) s = NEG_INF_F;
    keys[gt] = sortable_f32(s);
}

// K2: partial histograms — 4 blocks per batch, each hists one quarter of
// the keys in a private LDS 16384-bin histogram (staged uint4 loads).
__global__ __launch_bounds__(1024) void k_hist_part(
    const unsigned* __restrict__ keys, unsigned* __restrict__ phist)
{
    __shared__ unsigned h[SWS(NBS - 1) + 2];   // 16896 words = 67.6 KB
    int b = blockIdx.x >> 2;
    int p = blockIdx.x & 3;
    int t = threadIdx.x;

    for (int i = t; i < SWS(NBS - 1) + 2; i += 1024) h[i] = 0u;
    __syncthreads();

    const uint4* kb4 = (const uint4*)(keys + (size_t)b * N_ANCH + p * QKEYS);
    uint4 v[9];
    #pragma unroll
    for (int k = 0; k < 9; ++k) v[k] = kb4[t + 1024 * k];
    #pragma unroll
    for (int k = 0; k < 9; ++k) {
        atomicAdd(&h[SWS(v[k].x >> 18)], 1u);
        atomicAdd(&h[SWS(v[k].y >> 18)], 1u);
        atomicAdd(&h[SWS(v[k].z >> 18)], 1u);
        atomicAdd(&h[SWS(v[k].w >> 18)], 1u);
    }
    __syncthreads();

    unsigned* ph = phist + (size_t)blockIdx.x * NBS;
    for (int i = t; i < NBS; i += 1024) ph[i] = h[SWS(i)];
}

// K3: per batch — sum 4 partials, suffix-scan 16384 bins, find threshold T.
// Writes TWO binbase copies (read-only for rank, mutable for scatter slot
// allocation — rewritten every call, so no memset needed), plus thresh/cnt.
__global__ __launch_bounds__(1024) void k_thresh2(
    const unsigned* __restrict__ phist, unsigned* __restrict__ bbro,
    unsigned* __restrict__ bbmut, unsigned* __restrict__ thresh,
    unsigned* __restrict__ cnt)
{
    __shared__ unsigned h[SWS(NBS - 1) + 2];
    __shared__ unsigned csum[1024];
    __shared__ unsigned sT;

    int b = blockIdx.x;
    int t = threadIdx.x;
    if (t == 0) sT = 0;

    const unsigned* ph = phist + (size_t)b * 4 * NBS;
    for (int i = t; i < NBS; i += 1024) {
        unsigned s0 = ph[i];
        unsigned s1 = ph[NBS + i];
        unsigned s2 = ph[2 * NBS + i];
        unsigned s3 = ph[3 * NBS + i];
        h[SWS(i)] = s0 + s1 + s2 + s3;
    }
    __syncthreads();

    int base = t * 16;
    unsigned s = 0;
    for (int u = 0; u < 16; ++u) s += h[SWS(base + u)];
    csum[t] = s;
    __syncthreads();
    for (int off = 1; off < 1024; off <<= 1) {
        unsigned v = (t + off < 1024) ? csum[t + off] : 0u;
        __syncthreads();
        csum[t] += v;
        __syncthreads();
    }
    unsigned before = csum[t] - s;

    unsigned acc = before;
    for (int bin = base + 15; bin >= base; --bin) {
        unsigned hh = h[SWS(bin)];
        if (acc + hh >= PRE_NMS) { atomicMax(&sT, (unsigned)bin); break; }
        acc += hh;
    }
    __syncthreads();
    unsigned T = sT;

    acc = before;
    for (int bin = base + 15; bin >= base; --bin) {
        unsigned hh = h[SWS(bin)];
        if ((unsigned)bin == T) cnt[b] = acc + hh;
        h[SWS(bin)] = acc;
        acc += hh;
    }
    if (t == 0) thresh[b] = T;
    __syncthreads();

    unsigned* r = bbro + (size_t)b * NBS;
    unsigned* m = bbmut + (size_t)b * NBS;
    for (int i = t; i < NBS; i += 1024) {
        unsigned v = h[SWS(i)];
        r[i] = v;
        m[i] = v;
    }
}

// K4: bin-segmented scatter — slot allocated by atomicAdd on the mutable
// binbase copy, giving the absolute position in seg.
__global__ void k_scatter(
    const unsigned* __restrict__ keys, const unsigned* __restrict__ thresh,
    unsigned* __restrict__ bbmut, unsigned long long* __restrict__ seg)
{
    int gt = blockIdx.x * blockDim.x + threadIdx.x;
    int pix  = gt & (NPIX - 1);
    int rest = gt >> 14;
    int a = rest % A_NUM;
    int b = rest / A_NUM;

    unsigned key = keys[gt];
    unsigned bin = key >> 18;
    if (bin >= thresh[b]) {
        unsigned pos = atomicAdd(&bbmut[(size_t)b * NBS + bin], 1u);
        if (pos < SEGL) {
            unsigned idx = (unsigned)(pix * A_NUM + a);
            seg[(size_t)b * SEGL + pos] =
                ((unsigned long long)key << 32) | (unsigned long long)(0xFFFFFFFFu - idx);
        }
    }
}

// K5a: many-block counting rank (32 blocks x 256 thr per batch, all CUs).
__global__ __launch_bounds__(256) void k_rank(
    const unsigned long long* __restrict__ seg, const unsigned* __restrict__ cnt,
    const unsigned* __restrict__ bbro, unsigned* __restrict__ ridx)
{
    int b = blockIdx.x >> 5;
    int p = ((blockIdx.x & 31) << 8) + threadIdx.x;
    unsigned n = cnt[b];
    if (n > SEGL) n = SEGL;
    if (p >= (int)n) return;

    const unsigned long long* S = seg + (size_t)b * SEGL;
    unsigned long long key = S[p];
    unsigned bin = (unsigned)(key >> 50);
    const unsigned* bb = bbro + (size_t)b * NBS;
    unsigned base = bb[bin];
    unsigned end = (bin > 0) ? bb[bin - 1] : n;
    if (end > n) end = n;

    unsigned rank = base;
    unsigned q = base;
    for (; q + 8 <= end; q += 8) {
        unsigned long long v0 = S[q + 0], v1 = S[q + 1];
        unsigned long long v2 = S[q + 2], v3 = S[q + 3];
        unsigned long long v4 = S[q + 4], v5 = S[q + 5];
        unsigned long long v6 = S[q + 6], v7 = S[q + 7];
        rank += (unsigned)(v0 > key) + (unsigned)(v1 > key)
              + (unsigned)(v2 > key) + (unsigned)(v3 > key)
              + (unsigned)(v4 > key) + (unsigned)(v5 > key)
              + (unsigned)(v6 > key) + (unsigned)(v7 > key);
    }
    for (; q < end; ++q) rank += (unsigned)(S[q] > key);

    if (rank < PRE_NMS)
        ridx[(size_t)b * PRE_NMS + rank] = 0xFFFFFFFFu - (unsigned)(key & 0xFFFFFFFFull);
}

// K5b: decode one box per output rank across all CUs.
__global__ void k_decode2(
    const unsigned* __restrict__ ridx,
    const float* __restrict__ deltas, const float* __restrict__ im_info,
    const float* __restrict__ anchors, float* __restrict__ boxes)
{
    int gt = blockIdx.x * blockDim.x + threadIdx.x;
    if (gt >= B_NUM * PRE_NMS) return;
    int b = gt / PRE_NMS;
    int idx = (int)ridx[gt];
    float x1, y1, x2, y2; bool v;
    decode_box(b, idx, deltas, im_info, anchors, x1, y1, x2, y2, v);
    *(float4*)(boxes + (size_t)gt * 4) = make_float4(x1, y1, x2, y2);
}

// One row of a 64x64 suppression block (exact ref op order; div only in the
// proven +-6e-7*uni band — validated absmax=0 since round 6).
__device__ __forceinline__ unsigned long long iou_row(
    float4 bi, float ia, float jx1, float jy1, float jx2, float jy2, float ja)
{
    float xx1 = fmaxf(bi.x, jx1);
    float yy1 = fmaxf(bi.y, jy1);
    float xx2 = fminf(bi.z, jx2);
    float yy2 = fminf(bi.w, jy2);
    float iw = fmaxf(0.0f, __fadd_rn(__fsub_rn(xx2, xx1), 1.0f));
    float ih = fmaxf(0.0f, __fadd_rn(__fsub_rn(yy2, yy1), 1.0f));
    float inter = __fmul_rn(iw, ih);
    float uni = __fsub_rn(__fadd_rn(ia, ja), inter);
    float diff = __fsub_rn(inter, __fmul_rn(NMS_THRESH_F, uni));
    unsigned long long sup = __ballot(diff > 0.0f);
    unsigned long long band = __ballot(fabsf(diff) <= __fmul_rn(6e-7f, uni));
    if (band) {
        unsigned long long supd = __ballot(__fdiv_rn(inter, uni) > NMS_THRESH_F);
        sup = (sup & ~band) | (supd & band);
    }
    return sup;
}

// K6: IoU suppression bitmask for row-tiles R in [Rstart, ...), ngroups
// 8-column groups per batch. statep!=null: skip batch if its scan already
// finished (done flag) — the truncated-IoU tail. Layout mask[b][R][C][64].
__global__ __launch_bounds__(256) void k_iou_mask(
    const float* __restrict__ boxes, unsigned long long* __restrict__ mask,
    int Rstart, int ngroups, const char* __restrict__ statep)
{
    int bid = blockIdx.x;
    int b = bid / ngroups;
    int g = bid - b * ngroups;
    if (statep && ((const int*)(statep + (size_t)b * STATE_STRIDE))[1]) return;

    int R = Rstart;
    while (g >= ((RT_TILES - R + 7) >> 3)) { g -= (RT_TILES - R + 7) >> 3; ++R; }

    int wave = threadIdx.x >> 6;
    int lane = threadIdx.x & 63;
    const float* Bb = boxes + (size_t)b * PRE_NMS * 4;

    __shared__ float4 rb4[64];
    __shared__ float rba[64];
    if (threadIdx.x < 64) {
        int il = R * 64 + threadIdx.x;
        float4 rv = make_float4(0.f, 0.f, -1.f, -1.f);
        if (il < PRE_NMS) rv = *(const float4*)(Bb + 4 * (size_t)il);
        rb4[threadIdx.x] = rv;
        rba[threadIdx.x] = __fmul_rn(__fadd_rn(__fsub_rn(rv.z, rv.x), 1.0f),
                                     __fadd_rn(__fsub_rn(rv.w, rv.y), 1.0f));
    }
    __syncthreads();

    int C1 = R + g * 8 + wave * 2;
    int C2 = C1 + 1;
    if (C1 >= RT_TILES) return;   // tail waves idle (no barriers below)

    float j1x1 = 0.f, j1y1 = 0.f, j1x2 = -1.f, j1y2 = -1.f;
    float j2x1 = 0.f, j2y1 = 0.f, j2x2 = -1.f, j2y2 = -1.f;
    int j1 = C1 * 64 + lane;
    int j2 = C2 * 64 + lane;
    if (j1 < PRE_NMS) {
        float4 v = *(const float4*)(Bb + 4 * (size_t)j1);
        j1x1 = v.x; j1y1 = v.y; j1x2 = v.z; j1y2 = v.w;
    }
    if (C2 < RT_TILES && j2 < PRE_NMS) {
        float4 v = *(const float4*)(Bb + 4 * (size_t)j2);
        j2x1 = v.x; j2y1 = v.y; j2x2 = v.z; j2y2 = v.w;
    }
    float j1a = __fmul_rn(__fadd_rn(__fsub_rn(j1x2, j1x1), 1.0f),
                          __fadd_rn(__fsub_rn(j1y2, j1y1), 1.0f));
    float j2a = __fmul_rn(__fadd_rn(__fsub_rn(j2x2, j2x1), 1.0f),
                          __fadd_rn(__fsub_rn(j2y2, j2y1), 1.0f));

    unsigned long long w1 = 0ULL, w2 = 0ULL;
    if (C1 == R) {   // diagonal tile
        #pragma unroll 4
        for (int ri = 0; ri < 64; ++ri) {
            float4 bi = rb4[ri];
            float ia = rba[ri];
            unsigned long long s1 = iou_row(bi, ia, j1x1, j1y1, j1x2, j1y2, j1a)
                                    & (0xFFFFFFFFFFFFFFFEull << ri);
            unsigned long long s2 = iou_row(bi, ia, j2x1, j2y1, j2x2, j2y2, j2a);
            w1 = (lane == ri) ? s1 : w1;
            w2 = (lane == ri) ? s2 : w2;
        }
    } else {
        #pragma unroll 4
        for (int ri = 0; ri < 64; ++ri) {
            float4 bi = rb4[ri];
            float ia = rba[ri];
            unsigned long long s1 = iou_row(bi, ia, j1x1, j1y1, j1x2, j1y2, j1a);
            unsigned long long s2 = iou_row(bi, ia, j2x1, j2y1, j2x2, j2y2, j2a);
            w1 = (lane == ri) ? s1 : w1;
            w2 = (lane == ri) ? s2 : w2;
        }
    }

    unsigned long long* Mb = mask + (size_t)b * BQWORDS;
    Mb[(size_t)(R * RT_TILES + C1) * 64 + lane] = w1;
    if (C2 < RT_TILES)
        Mb[(size_t)(R * RT_TILES + C2) * 64 + lane] = w2;
}

// K7: greedy scan over rows [row_begin,row_end), resumable. One wave/batch.
// Round-22: suppression state lives in REGISTERS (lane l owns words l and
// 64+l); the bit-test word curw is maintained via cross-lane __shfl instead
// of a dependent LDS round-trip per kept row (measured 257 cy/row -> the
// LDS supp[] read latency dominated). klist writes stay in LDS (rare).
__global__ __launch_bounds__(64) void k_nms_scan_part(
    const unsigned long long* __restrict__ mask,
    const float* __restrict__ boxes, float* __restrict__ out,
    char* __restrict__ statep, int row_begin, int row_end, int final_phase)
{
    const int b = blockIdx.x;
    const int l = threadIdx.x;
    char* st = statep + (size_t)b * STATE_STRIDE;
    int* s_meta = (int*)st;
    unsigned long long* s_supp = (unsigned long long*)(st + 16);
    int* s_klist = (int*)(st + 768);

    __shared__ int klist[POST_NMS];
    unsigned long long reg0, reg1;   // suppression words l and 64+l
    int kept, done;

    if (row_begin == 0) {
        reg0 = 0ULL; reg1 = 0ULL;
        kept = 0; done = 0;
    } else {
        kept = s_meta[0];
        done = s_meta[1];
        reg0 = s_supp[l];
        reg1 = (l < RT_TILES - 64) ? s_supp[64 + l] : 0ULL;
        for (int k = l; k < POST_NMS; k += 64) klist[k] = s_klist[k];
    }
    __syncthreads();

    const unsigned long long* __restrict__ M = mask + (size_t)b * BQWORDS;
    unsigned long long curw = 0; int curwi = -1;

#define LOADROW(p0, p1, i) { \
        int _i = ((i) < PRE_NMS) ? (i) : (PRE_NMS - 1); \
        int _R = _i >> 6; \
        const unsigned long long* _r = M + (size_t)(_R * RT_TILES) * 64 + (_i & 63); \
        p0 = 0ULL; p1 = 0ULL; \
        if (l >= _R) p0 = _r[l * 64]; \
        if (l < RT_TILES - 64 && 64 + l >= _R) p1 = _r[(64 + l) * 64]; }

#define STEP(i, p0, p1) { \
        if (kept < POST_NMS) { \
            int _wi = (i) >> 6; \
            if (_wi != curwi) { \
                curw = (_wi < 64) ? __shfl(reg0, _wi) : __shfl(reg1, _wi - 64); \
                curwi = _wi; \
            } \
            if (!((curw >> ((i) & 63)) & 1ULL)) { \
                if (l == 0) klist[kept] = (i); \
                unsigned long long _d = (_wi < 64) ? __shfl(p0, _wi) \
                                                   : __shfl(p1, _wi - 64); \
                reg0 |= p0; \
                reg1 |= p1; \
                curw |= _d; \
                ++kept; \
            } \
        } }

    if (!done && kept < POST_NMS) {
        unsigned long long p[16][2];
        #pragma unroll
        for (int k = 0; k < 16; ++k) { LOADROW(p[k][0], p[k][1], row_begin + k) }

        for (int i = row_begin; i < row_end && kept < POST_NMS; i += 16) {
            #pragma unroll
            for (int k = 0; k < 16; ++k) {
                STEP(i + k, p[k][0], p[k][1])
                LOADROW(p[k][0], p[k][1], i + 16 + k)
            }
        }
    }
    __syncthreads();

    if (!final_phase) {
        if (l == 0) { s_meta[0] = kept; s_meta[1] = (kept >= POST_NMS) ? 1 : 0; }
        s_supp[l] = reg0;
        if (l < RT_TILES - 64) s_supp[64 + l] = reg1;
        for (int k = l; k < POST_NMS; k += 64) s_klist[k] = klist[k];
    } else {
        for (int k = l; k < POST_NMS; k += 64) {
            size_t o = ((size_t)b * POST_NMS + k) * 5;
            float x1 = 0.f, y1 = 0.f, x2 = 0.f, y2 = 0.f;
            if (k < kept) {
                int idx = klist[k];
                const float4 v = *(const float4*)(boxes + ((size_t)b * PRE_NMS + idx) * 4);
                x1 = v.x; y1 = v.y; x2 = v.z; y2 = v.w;
            }
            out[o + 0] = (float)b;
            out[o + 1] = x1; out[o + 2] = y1; out[o + 3] = x2; out[o + 4] = y2;
        }
    }
#undef LOADROW
#undef STEP
}

// Fallback NMS (used only if ws_size is too small for the bitmask).
__global__ __launch_bounds__(1024) void k_nms_out(
    const float* __restrict__ boxes, float* __restrict__ out)
{
    __shared__ float bx1[PRE_NMS], by1[PRE_NMS], bx2[PRE_NMS], by2[PRE_NMS], bar[PRE_NMS];
    __shared__ unsigned rem[(PRE_NMS + 31) / 32];
    __shared__ int kept_idx[POST_NMS];

    int b = blockIdx.x;
    int t = threadIdx.x;

    for (int p = t; p < PRE_NMS; p += 1024) {
        size_t o = ((size_t)b * PRE_NMS + p) * 4;
        float x1 = boxes[o], y1 = boxes[o + 1], x2 = boxes[o + 2], y2 = boxes[o + 3];
        bx1[p] = x1; by1[p] = y1; bx2[p] = x2; by2[p] = y2;
        bar[p] = __fmul_rn(__fadd_rn(__fsub_rn(x2, x1), 1.0f),
                           __fadd_rn(__fsub_rn(y2, y1), 1.0f));
    }
    for (int p = t; p < (PRE_NMS + 31) / 32; p += 1024) rem[p] = 0u;
    __syncthreads();

    int kept = 0;
    for (int i = 0; i < PRE_NMS && kept < POST_NMS; ++i) {
        if (rem[i >> 5] & (1u << (i & 31))) continue;
        if (t == 0) kept_idx[kept] = i;
        float xi1 = bx1[i], yi1 = by1[i], xi2 = bx2[i], yi2 = by2[i], ai = bar[i];
        for (int j = i + 1 + t; j < PRE_NMS; j += 1024) {
            float xx1 = fmaxf(xi1, bx1[j]);
            float yy1 = fmaxf(yi1, by1[j]);
            float xx2 = fminf(xi2, bx2[j]);
            float yy2 = fminf(yi2, by2[j]);
            float iw = fmaxf(0.0f, __fadd_rn(__fsub_rn(xx2, xx1), 1.0f));
            float ih = fmaxf(0.0f, __fadd_rn(__fsub_rn(yy2, yy1), 1.0f));
            float inter = __fmul_rn(iw, ih);
            if (inter > 0.0f) {
                float uni = __fsub_rn(__fadd_rn(ai, bar[j]), inter);
                float iou = __fdiv_rn(inter, uni);
                if (iou > NMS_THRESH_F) atomicOr(&rem[j >> 5], 1u << (j & 31));
            }
        }
        ++kept;
        __syncthreads();
    }

    for (int k = t; k < POST_NMS; k += 1024) {
        size_t o = ((size_t)b * POST_NMS + k) * 5;
        out[o] = (float)b;
        if (k < kept) {
            int ii = kept_idx[k];
            out[o + 1] = bx1[ii]; out[o + 2] = by1[ii];
            out[o + 3] = bx2[ii]; out[o + 4] = by2[ii];
        } else {
            out[o + 1] = 0.0f; out[o + 2] = 0.0f; out[o + 3] = 0.0f; out[o + 4] = 0.0f;
        }
    }
}

extern "C" void kernel_launch(void* const* d_in, const int* in_sizes, int n_in,
                              void* d_out, int out_size, void* d_ws, size_t ws_size,
                              hipStream_t stream)
{
    const float* scores  = (const float*)d_in[0];
    const float* deltas  = (const float*)d_in[1];
    const float* im_info = (const float*)d_in[2];
    const float* anchors = (const float*)d_in[3];
    float* out = (float*)d_out;
    char* ws = (char*)d_ws;

    unsigned* keys             = (unsigned*)(ws + OFF_KEYS);
    float* boxes               = (float*)(ws + OFF_BOXES);
    unsigned* phist            = (unsigned*)(ws + OFF_PHIST);
    unsigned* bbro             = (unsigned*)(ws + OFF_BBRO);
    unsigned* bbmut            = (unsigned*)(ws + OFF_BBMUT);
    unsigned* thresh           = (unsigned*)(ws + OFF_CNT);
    unsigned* cnt              = thresh + 8;
    unsigned long long* seg    = (unsigned long long*)(ws + OFF_SEG);
    unsigned* ridx             = (unsigned*)(ws + OFF_RIDX);
    char* state                = (char*)(ws + OFF_STATE);
    unsigned long long* mask   = (unsigned long long*)(ws + OFF_MASK);

    int total = B_NUM * N_ANCH;
    int blk = 256;
    k_decode<<<(total + blk - 1) / blk, blk, 0, stream>>>(
        scores, deltas, im_info, anchors, keys);
    k_hist_part<<<B_NUM * 4, 1024, 0, stream>>>(keys, phist);
    k_thresh2<<<B_NUM, 1024, 0, stream>>>(phist, bbro, bbmut, thresh, cnt);
    k_scatter<<<(total + blk - 1) / blk, blk, 0, stream>>>(
        keys, thresh, bbmut, seg);
    k_rank<<<B_NUM * 32, 256, 0, stream>>>(seg, cnt, bbro, ridx);
    k_decode2<<<(B_NUM * PRE_NMS + blk - 1) / blk, blk, 0, stream>>>(
        ridx, deltas, im_info, anchors, boxes);

    if (ws_size >= (size_t)OFF_MASK + MASK_BYTES) {
        // phase A: rows 0..1023 only
        k_iou_mask<<<B_NUM * G_HEAD, 256, 0, stream>>>(
            boxes, mask, 0, G_HEAD, (const char*)0);
        // scan p1: early-stop within rows < 1024; persist state + done flag
        k_nms_scan_part<<<B_NUM, 64, 0, stream>>>(
            mask, boxes, out, state, 0, ROWS_SPLIT, 0);
        // tail: rows >= 1024, skipped per batch when done
        k_iou_mask<<<B_NUM * G_TAIL, 256, 0, stream>>>(
            boxes, mask, R_SPLIT, G_TAIL, (const char*)state);
        // scan p2: finish (or just write output if already done)
        k_nms_scan_part<<<B_NUM, 64, 0, stream>>>(
            mask, boxes, out, state, ROWS_SPLIT, PRE_NMS, 1);
    } else {
        k_nms_out<<<B_NUM, 1024, 0, stream>>>(boxes, out);
    }
}

// Round 23
// 204.974 us; speedup vs baseline: 1.8892x; 1.0446x over previous
//
#include <hip/hip_runtime.h>
#include <stdint.h>

#define FEAT_STRIDE_I 16
#define A_NUM 9
#define HH 128
#define WW 128
#define NPIX (HH * WW)            // 16384
#define N_ANCH (NPIX * A_NUM)     // 147456
#define B_NUM 8
#define PRE_NMS 6000
#define POST_NMS 300
#define NMS_THRESH_F 0.7f
#define MIN_SIZE_F 16.0f
#define NEG_INF_F -1e30f

#define NBS 16384                  // 14-bit bins (key>>18)
#define SWS(i) ((i) + ((i) >> 5))  // LDS swizzle
#define SEGL 8192                  // candidate segment cap (cnt ~6700 max)
#define QKEYS (N_ANCH / 4)         // 36864 keys per hist part

#define RT_TILES 94                // ceil(6000/64)
#define GT_TILES 600               // sum_R ceil((94-R)/8): 8-column groups
#define BQWORDS (RT_TILES * RT_TILES * 64)   // 565,504 qwords per batch

// truncated-IoU split: phase A computes row-tiles R < R_SPLIT (rows 0..1023);
// the tail (R >= R_SPLIT) is skipped per batch when the scan already kept 300.
#define R_SPLIT 16
#define ROWS_SPLIT (R_SPLIT * 64)  // 1024
#define G_HEAD 180                 // sum_{R=0..15} (101-R)>>3
#define G_TAIL (GT_TILES - G_HEAD) // 420
#define STATE_STRIDE 2048          // per-batch scan state (kept,done,supp,klist)
#define TMQ (ROWS_SPLIT * RT_TILES)            // 96,256 qwords per batch

// ---- workspace layout (bytes) ----
// KEYS and PHIST are dead by the time k_transpose runs; the row-major head
// mask (TMASK, 6,160,384 B) overlays them — no extra ws needed.
#define OFF_KEYS    0u             // 8*147456*4 = 4,718,592
#define OFF_PHIST   4718592u       // 8*4*16384*4 = 2,097,152 -> ends 6,815,744
#define OFF_TMASK   0u             // 8*96256*8 = 6,160,384 (overlay, late-use)
#define OFF_BOXES   6815744u       // 8*6000*4*4 = 768,000
#define OFF_BBRO    7583744u       // 8*16384*4 = 524,288 (read-only binbase)
#define OFF_BBMUT   8108032u       // 524,288 (scatter slot counters)
#define OFF_CNT     8632320u       // thresh[8] + cnt[8] (512 B)
#define OFF_SEG     8632832u       // 8*8192*8 = 524,288
#define OFF_RIDX    9157120u       // 8*6000*4 = 192,000
#define OFF_STATE   9349120u       // 8*2048 = 16,384
#define OFF_MASK    9365504u       // 36,192,256 -> end 45,557,760
#define MASK_BYTES ((size_t)B_NUM * BQWORDS * 8)

__device__ __forceinline__ unsigned sortable_f32(float f) {
    unsigned u = __float_as_uint(f);
    return (u & 0x80000000u) ? ~u : (u | 0x80000000u);
}

// Decode one anchor's box exactly in the reference's op order.
__device__ __forceinline__ void decode_box(
    int b, int idx,
    const float* __restrict__ deltas, const float* __restrict__ im_info,
    const float* __restrict__ anchors,
    float& x1, float& y1, float& x2, float& y2, bool& valid)
{
    int a   = idx % A_NUM;
    int pix = idx / A_NUM;
    int w   = pix & (WW - 1);
    int h   = pix >> 7;

    float a0 = anchors[a * 4 + 0];
    float a1 = anchors[a * 4 + 1];
    float a2 = anchors[a * 4 + 2];
    float a3 = anchors[a * 4 + 3];

    float aw = __fadd_rn(__fsub_rn(a2, a0), 1.0f);
    float ah = __fadd_rn(__fsub_rn(a3, a1), 1.0f);
    float sx = (float)(w * FEAT_STRIDE_I);
    float sy = (float)(h * FEAT_STRIDE_I);
    float acx = __fadd_rn(__fadd_rn(sx, a0), __fmul_rn(0.5f, aw));
    float acy = __fadd_rn(__fadd_rn(sy, a1), __fmul_rn(0.5f, ah));

    size_t base = ((size_t)b * 36 + 4 * a) * NPIX + pix;
    float dx = deltas[base];
    float dy = deltas[base + NPIX];
    float dw = deltas[base + 2 * (size_t)NPIX];
    float dh = deltas[base + 3 * (size_t)NPIX];

    float pcx = __fadd_rn(__fmul_rn(dx, aw), acx);
    float pcy = __fadd_rn(__fmul_rn(dy, ah), acy);
    float pw  = __fmul_rn(expf(dw), aw);
    float ph  = __fmul_rn(expf(dh), ah);

    float hx = __fmul_rn(0.5f, pw);
    float hy = __fmul_rn(0.5f, ph);
    x1 = __fsub_rn(pcx, hx);
    y1 = __fsub_rn(pcy, hy);
    x2 = __fadd_rn(pcx, hx);
    y2 = __fadd_rn(pcy, hy);

    float im_h = im_info[b * 3 + 0];
    float im_w = im_info[b * 3 + 1];
    float sc   = im_info[b * 3 + 2];
    float wmax = __fsub_rn(im_w, 1.0f);
    float hmax = __fsub_rn(im_h, 1.0f);

    x1 = fminf(fmaxf(x1, 0.0f), wmax);
    y1 = fminf(fmaxf(y1, 0.0f), hmax);
    x2 = fminf(fmaxf(x2, 0.0f), wmax);
    y2 = fminf(fmaxf(y2, 0.0f), hmax);

    float min_sz = __fmul_rn(MIN_SIZE_F, sc);
    valid = (__fadd_rn(__fsub_rn(x2, x1), 1.0f) >= min_sz) &&
            (__fadd_rn(__fsub_rn(y2, y1), 1.0f) >= min_sz);
}

// K1: decode + masked score -> sortable key. Pure streaming, no atomics.
__global__ void k_decode(
    const float* __restrict__ scores, const float* __restrict__ deltas,
    const float* __restrict__ im_info, const float* __restrict__ anchors,
    unsigned* __restrict__ keys)
{
    int gt = blockIdx.x * blockDim.x + threadIdx.x;
    if (gt >= B_NUM * N_ANCH) return;
    int pix  = gt & (NPIX - 1);
    int rest = gt >> 14;
    int a = rest % A_NUM;
    int b = rest / A_NUM;
    int idx = pix * A_NUM + a;

    float x1, y1, x2, y2; bool valid;
    decode_box(b, idx, deltas, im_info, anchors, x1, y1, x2, y2, valid);

    float s = scores[((size_t)b * 18 + 9 + a) * NPIX + pix];
    if (!valid) s = NEG_INF_F;
    keys[gt] = sortable_f32(s);
}

// K2: partial histograms — 4 blocks per batch, each hists one quarter of
// the keys in a private LDS 16384-bin histogram (staged uint4 loads).
__global__ __launch_bounds__(1024) void k_hist_part(
    const unsigned* __restrict__ keys, unsigned* __restrict__ phist)
{
    __shared__ unsigned h[SWS(NBS - 1) + 2];   // 16896 words = 67.6 KB
    int b = blockIdx.x >> 2;
    int p = blockIdx.x & 3;
    int t = threadIdx.x;

    for (int i = t; i < SWS(NBS - 1) + 2; i += 1024) h[i] = 0u;
    __syncthreads();

    const uint4* kb4 = (const uint4*)(keys + (size_t)b * N_ANCH + p * QKEYS);
    uint4 v[9];
    #pragma unroll
    for (int k = 0; k < 9; ++k) v[k] = kb4[t + 1024 * k];
    #pragma unroll
    for (int k = 0; k < 9; ++k) {
        atomicAdd(&h[SWS(v[k].x >> 18)], 1u);
        atomicAdd(&h[SWS(v[k].y >> 18)], 1u);
        atomicAdd(&h[SWS(v[k].z >> 18)], 1u);
        atomicAdd(&h[SWS(v[k].w >> 18)], 1u);
    }
    __syncthreads();

    unsigned* ph = phist + (size_t)blockIdx.x * NBS;
    for (int i = t; i < NBS; i += 1024) ph[i] = h[SWS(i)];
}

// K3: per batch — sum 4 partials, suffix-scan 16384 bins, find threshold T.
__global__ __launch_bounds__(1024) void k_thresh2(
    const unsigned* __restrict__ phist, unsigned* __restrict__ bbro,
    unsigned* __restrict__ bbmut, unsigned* __restrict__ thresh,
    unsigned* __restrict__ cnt)
{
    __shared__ unsigned h[SWS(NBS - 1) + 2];
    __shared__ unsigned csum[1024];
    __shared__ unsigned sT;

    int b = blockIdx.x;
    int t = threadIdx.x;
    if (t == 0) sT = 0;

    const unsigned* ph = phist + (size_t)b * 4 * NBS;
    for (int i = t; i < NBS; i += 1024) {
        unsigned s0 = ph[i];
        unsigned s1 = ph[NBS + i];
        unsigned s2 = ph[2 * NBS + i];
        unsigned s3 = ph[3 * NBS + i];
        h[SWS(i)] = s0 + s1 + s2 + s3;
    }
    __syncthreads();

    int base = t * 16;
    unsigned s = 0;
    for (int u = 0; u < 16; ++u) s += h[SWS(base + u)];
    csum[t] = s;
    __syncthreads();
    for (int off = 1; off < 1024; off <<= 1) {
        unsigned v = (t + off < 1024) ? csum[t + off] : 0u;
        __syncthreads();
        csum[t] += v;
        __syncthreads();
    }
    unsigned before = csum[t] - s;

    unsigned acc = before;
    for (int bin = base + 15; bin >= base; --bin) {
        unsigned hh = h[SWS(bin)];
        if (acc + hh >= PRE_NMS) { atomicMax(&sT, (unsigned)bin); break; }
        acc += hh;
    }
    __syncthreads();
    unsigned T = sT;

    acc = before;
    for (int bin = base + 15; bin >= base; --bin) {
        unsigned hh = h[SWS(bin)];
        if ((unsigned)bin == T) cnt[b] = acc + hh;
        h[SWS(bin)] = acc;
        acc += hh;
    }
    if (t == 0) thresh[b] = T;
    __syncthreads();

    unsigned* r = bbro + (size_t)b * NBS;
    unsigned* m = bbmut + (size_t)b * NBS;
    for (int i = t; i < NBS; i += 1024) {
        unsigned v = h[SWS(i)];
        r[i] = v;
        m[i] = v;
    }
}

// K4: bin-segmented scatter — slot allocated by atomicAdd on the mutable
// binbase copy, giving the absolute position in seg.
__global__ void k_scatter(
    const unsigned* __restrict__ keys, const unsigned* __restrict__ thresh,
    unsigned* __restrict__ bbmut, unsigned long long* __restrict__ seg)
{
    int gt = blockIdx.x * blockDim.x + threadIdx.x;
    int pix  = gt & (NPIX - 1);
    int rest = gt >> 14;
    int a = rest % A_NUM;
    int b = rest / A_NUM;

    unsigned key = keys[gt];
    unsigned bin = key >> 18;
    if (bin >= thresh[b]) {
        unsigned pos = atomicAdd(&bbmut[(size_t)b * NBS + bin], 1u);
        if (pos < SEGL) {
            unsigned idx = (unsigned)(pix * A_NUM + a);
            seg[(size_t)b * SEGL + pos] =
                ((unsigned long long)key << 32) | (unsigned long long)(0xFFFFFFFFu - idx);
        }
    }
}

// K5a: many-block counting rank (32 blocks x 256 thr per batch, all CUs).
__global__ __launch_bounds__(256) void k_rank(
    const unsigned long long* __restrict__ seg, const unsigned* __restrict__ cnt,
    const unsigned* __restrict__ bbro, unsigned* __restrict__ ridx)
{
    int b = blockIdx.x >> 5;
    int p = ((blockIdx.x & 31) << 8) + threadIdx.x;
    unsigned n = cnt[b];
    if (n > SEGL) n = SEGL;
    if (p >= (int)n) return;

    const unsigned long long* S = seg + (size_t)b * SEGL;
    unsigned long long key = S[p];
    unsigned bin = (unsigned)(key >> 50);
    const unsigned* bb = bbro + (size_t)b * NBS;
    unsigned base = bb[bin];
    unsigned end = (bin > 0) ? bb[bin - 1] : n;
    if (end > n) end = n;

    unsigned rank = base;
    unsigned q = base;
    for (; q + 8 <= end; q += 8) {
        unsigned long long v0 = S[q + 0], v1 = S[q + 1];
        unsigned long long v2 = S[q + 2], v3 = S[q + 3];
        unsigned long long v4 = S[q + 4], v5 = S[q + 5];
        unsigned long long v6 = S[q + 6], v7 = S[q + 7];
        rank += (unsigned)(v0 > key) + (unsigned)(v1 > key)
              + (unsigned)(v2 > key) + (unsigned)(v3 > key)
              + (unsigned)(v4 > key) + (unsigned)(v5 > key)
              + (unsigned)(v6 > key) + (unsigned)(v7 > key);
    }
    for (; q < end; ++q) rank += (unsigned)(S[q] > key);

    if (rank < PRE_NMS)
        ridx[(size_t)b * PRE_NMS + rank] = 0xFFFFFFFFu - (unsigned)(key & 0xFFFFFFFFull);
}

// K5b: decode one box per output rank across all CUs.
__global__ void k_decode2(
    const unsigned* __restrict__ ridx,
    const float* __restrict__ deltas, const float* __restrict__ im_info,
    const float* __restrict__ anchors, float* __restrict__ boxes)
{
    int gt = blockIdx.x * blockDim.x + threadIdx.x;
    if (gt >= B_NUM * PRE_NMS) return;
    int b = gt / PRE_NMS;
    int idx = (int)ridx[gt];
    float x1, y1, x2, y2; bool v;
    decode_box(b, idx, deltas, im_info, anchors, x1, y1, x2, y2, v);
    *(float4*)(boxes + (size_t)gt * 4) = make_float4(x1, y1, x2, y2);
}

// One row of a 64x64 suppression block (exact ref op order; div only in the
// proven +-6e-7*uni band — validated absmax=0 since round 6).
__device__ __forceinline__ unsigned long long iou_row(
    float4 bi, float ia, float jx1, float jy1, float jx2, float jy2, float ja)
{
    float xx1 = fmaxf(bi.x, jx1);
    float yy1 = fmaxf(bi.y, jy1);
    float xx2 = fminf(bi.z, jx2);
    float yy2 = fminf(bi.w, jy2);
    float iw = fmaxf(0.0f, __fadd_rn(__fsub_rn(xx2, xx1), 1.0f));
    float ih = fmaxf(0.0f, __fadd_rn(__fsub_rn(yy2, yy1), 1.0f));
    float inter = __fmul_rn(iw, ih);
    float uni = __fsub_rn(__fadd_rn(ia, ja), inter);
    float diff = __fsub_rn(inter, __fmul_rn(NMS_THRESH_F, uni));
    unsigned long long sup = __ballot(diff > 0.0f);
    unsigned long long band = __ballot(fabsf(diff) <= __fmul_rn(6e-7f, uni));
    if (band) {
        unsigned long long supd = __ballot(__fdiv_rn(inter, uni) > NMS_THRESH_F);
        sup = (sup & ~band) | (supd & band);
    }
    return sup;
}

// K6: IoU suppression bitmask for row-tiles R in [Rstart, ...), ngroups
// 8-column groups per batch. statep!=null: skip batch if its scan already
// finished (done flag). Layout mask[b][R][C][64].
__global__ __launch_bounds__(256) void k_iou_mask(
    const float* __restrict__ boxes, unsigned long long* __restrict__ mask,
    int Rstart, int ngroups, const char* __restrict__ statep)
{
    int bid = blockIdx.x;
    int b = bid / ngroups;
    int g = bid - b * ngroups;
    if (statep && ((const int*)(statep + (size_t)b * STATE_STRIDE))[1]) return;

    int R = Rstart;
    while (g >= ((RT_TILES - R + 7) >> 3)) { g -= (RT_TILES - R + 7) >> 3; ++R; }

    int wave = threadIdx.x >> 6;
    int lane = threadIdx.x & 63;
    const float* Bb = boxes + (size_t)b * PRE_NMS * 4;

    __shared__ float4 rb4[64];
    __shared__ float rba[64];
    if (threadIdx.x < 64) {
        int il = R * 64 + threadIdx.x;
        float4 rv = make_float4(0.f, 0.f, -1.f, -1.f);
        if (il < PRE_NMS) rv = *(const float4*)(Bb + 4 * (size_t)il);
        rb4[threadIdx.x] = rv;
        rba[threadIdx.x] = __fmul_rn(__fadd_rn(__fsub_rn(rv.z, rv.x), 1.0f),
                                     __fadd_rn(__fsub_rn(rv.w, rv.y), 1.0f));
    }
    __syncthreads();

    int C1 = R + g * 8 + wave * 2;
    int C2 = C1 + 1;
    if (C1 >= RT_TILES) return;   // tail waves idle (no barriers below)

    float j1x1 = 0.f, j1y1 = 0.f, j1x2 = -1.f, j1y2 = -1.f;
    float j2x1 = 0.f, j2y1 = 0.f, j2x2 = -1.f, j2y2 = -1.f;
    int j1 = C1 * 64 + lane;
    int j2 = C2 * 64 + lane;
    if (j1 < PRE_NMS) {
        float4 v = *(const float4*)(Bb + 4 * (size_t)j1);
        j1x1 = v.x; j1y1 = v.y; j1x2 = v.z; j1y2 = v.w;
    }
    if (C2 < RT_TILES && j2 < PRE_NMS) {
        float4 v = *(const float4*)(Bb + 4 * (size_t)j2);
        j2x1 = v.x; j2y1 = v.y; j2x2 = v.z; j2y2 = v.w;
    }
    float j1a = __fmul_rn(__fadd_rn(__fsub_rn(j1x2, j1x1), 1.0f),
                          __fadd_rn(__fsub_rn(j1y2, j1y1), 1.0f));
    float j2a = __fmul_rn(__fadd_rn(__fsub_rn(j2x2, j2x1), 1.0f),
                          __fadd_rn(__fsub_rn(j2y2, j2y1), 1.0f));

    unsigned long long w1 = 0ULL, w2 = 0ULL;
    if (C1 == R) {   // diagonal tile
        #pragma unroll 4
        for (int ri = 0; ri < 64; ++ri) {
            float4 bi = rb4[ri];
            float ia = rba[ri];
            unsigned long long s1 = iou_row(bi, ia, j1x1, j1y1, j1x2, j1y2, j1a)
                                    & (0xFFFFFFFFFFFFFFFEull << ri);
            unsigned long long s2 = iou_row(bi, ia, j2x1, j2y1, j2x2, j2y2, j2a);
            w1 = (lane == ri) ? s1 : w1;
            w2 = (lane == ri) ? s2 : w2;
        }
    } else {
        #pragma unroll 4
        for (int ri = 0; ri < 64; ++ri) {
            float4 bi = rb4[ri];
            float ia = rba[ri];
            unsigned long long s1 = iou_row(bi, ia, j1x1, j1y1, j1x2, j1y2, j1a);
            unsigned long long s2 = iou_row(bi, ia, j2x1, j2y1, j2x2, j2y2, j2a);
            w1 = (lane == ri) ? s1 : w1;
            w2 = (lane == ri) ? s2 : w2;
        }
    }

    unsigned long long* Mb = mask + (size_t)b * BQWORDS;
    Mb[(size_t)(R * RT_TILES + C1) * 64 + lane] = w1;
    if (C2 < RT_TILES)
        Mb[(size_t)(R * RT_TILES + C2) * 64 + lane] = w2;
}

// K6b: transpose head mask [R][C][64] -> row-major tmask[i][C] for rows
// < ROWS_SPLIT. Scan p1's per-row load becomes 94 CONTIGUOUS qwords
// (12 cache lines) instead of 94 lines at stride 512B — the measured
// 164cy/row was L2 request-rate on the strided row gather.
__global__ __launch_bounds__(1024) void k_transpose(
    const unsigned long long* __restrict__ mask,
    unsigned long long* __restrict__ tmask)
{
    __shared__ unsigned long long tile[64 * RT_TILES];   // 48,128 B
    int b = blockIdx.x >> 4;
    int R = blockIdx.x & 15;
    int t = threadIdx.x;
    const unsigned long long* Mb =
        mask + (size_t)b * BQWORDS + (size_t)R * RT_TILES * 64;
    for (int idx = t; idx < RT_TILES * 64; idx += 1024) {
        int C = idx >> 6, r = idx & 63;
        tile[r * RT_TILES + C] = Mb[(size_t)C * 64 + r];
    }
    __syncthreads();
    unsigned long long* Tb =
        tmask + (size_t)b * TMQ + (size_t)R * 64 * RT_TILES;
    for (int idx = t; idx < 64 * RT_TILES; idx += 1024)
        Tb[idx] = tile[idx];
}

// K7: greedy scan, resumable. One wave/batch. Suppression state in
// registers (lane l owns words l, 64+l); curw via cross-lane shuffle.
// p1 (final_phase==0) reads the ROW-MAJOR tmask (coalesced rows, incl.
// C<R garbage — safe: those bits map to already-decided j, the semantics
// validated absmax=0 in rounds 5-9). p2 reads the original mask layout.
__global__ __launch_bounds__(64) void k_nms_scan_part(
    const unsigned long long* __restrict__ mask,
    const unsigned long long* __restrict__ tmask,
    const float* __restrict__ boxes, float* __restrict__ out,
    char* __restrict__ statep, int row_begin, int row_end, int final_phase)
{
    const int b = blockIdx.x;
    const int l = threadIdx.x;
    char* st = statep + (size_t)b * STATE_STRIDE;
    int* s_meta = (int*)st;
    unsigned long long* s_supp = (unsigned long long*)(st + 16);
    int* s_klist = (int*)(st + 768);

    __shared__ int klist[POST_NMS];
    unsigned long long reg0, reg1;   // suppression words l and 64+l
    int kept, done;

    if (row_begin == 0) {
        reg0 = 0ULL; reg1 = 0ULL;
        kept = 0; done = 0;
    } else {
        kept = s_meta[0];
        done = s_meta[1];
        reg0 = s_supp[l];
        reg1 = (l < RT_TILES - 64) ? s_supp[64 + l] : 0ULL;
        for (int k = l; k < POST_NMS; k += 64) klist[k] = s_klist[k];
    }
    __syncthreads();

    const unsigned long long* __restrict__ M = mask + (size_t)b * BQWORDS;
    const unsigned long long* __restrict__ TM = tmask + (size_t)b * TMQ;
    unsigned long long curw = 0; int curwi = -1;

#define LOADROW_T(p0, p1, i) { \
        int _i = ((i) < ROWS_SPLIT) ? (i) : (ROWS_SPLIT - 1); \
        const unsigned long long* _r = TM + (size_t)_i * RT_TILES; \
        p0 = _r[l]; \
        p1 = (l < RT_TILES - 64) ? _r[64 + l] : 0ULL; }

#define LOADROW(p0, p1, i) { \
        int _i = ((i) < PRE_NMS) ? (i) : (PRE_NMS - 1); \
        int _R = _i >> 6; \
        const unsigned long long* _r = M + (size_t)(_R * RT_TILES) * 64 + (_i & 63); \
        p0 = 0ULL; p1 = 0ULL; \
        if (l >= _R) p0 = _r[l * 64]; \
        if (l < RT_TILES - 64 && 64 + l >= _R) p1 = _r[(64 + l) * 64]; }

#define STEP(i, p0, p1) { \
        if (kept < POST_NMS) { \
            int _wi = (i) >> 6; \
            if (_wi != curwi) { \
                curw = (_wi < 64) ? __shfl(reg0, _wi) : __shfl(reg1, _wi - 64); \
                curwi = _wi; \
            } \
            if (!((curw >> ((i) & 63)) & 1ULL)) { \
                if (l == 0) klist[kept] = (i); \
                unsigned long long _d = (_wi < 64) ? __shfl(p0, _wi) \
                                                   : __shfl(p1, _wi - 64); \
                reg0 |= p0; \
                reg1 |= p1; \
                curw |= _d; \
                ++kept; \
            } \
        } }

    if (!done && kept < POST_NMS) {
        unsigned long long p[16][2];
        if (!final_phase) {
            #pragma unroll
            for (int k = 0; k < 16; ++k) { LOADROW_T(p[k][0], p[k][1], row_begin + k) }
            for (int i = row_begin; i < row_end && kept < POST_NMS; i += 16) {
                #pragma unroll
                for (int k = 0; k < 16; ++k) {
                    STEP(i + k, p[k][0], p[k][1])
                    LOADROW_T(p[k][0], p[k][1], i + 16 + k)
                }
            }
        } else {
            #pragma unroll
            for (int k = 0; k < 16; ++k) { LOADROW(p[k][0], p[k][1], row_begin + k) }
            for (int i = row_begin; i < row_end && kept < POST_NMS; i += 16) {
                #pragma unroll
                for (int k = 0; k < 16; ++k) {
                    STEP(i + k, p[k][0], p[k][1])
                    LOADROW(p[k][0], p[k][1], i + 16 + k)
                }
            }
        }
    }
    __syncthreads();

    if (!final_phase) {
        if (l == 0) { s_meta[0] = kept; s_meta[1] = (kept >= POST_NMS) ? 1 : 0; }
        s_supp[l] = reg0;
        if (l < RT_TILES - 64) s_supp[64 + l] = reg1;
        for (int k = l; k < POST_NMS; k += 64) s_klist[k] = klist[k];
    } else {
        for (int k = l; k < POST_NMS; k += 64) {
            size_t o = ((size_t)b * POST_NMS + k) * 5;
            float x1 = 0.f, y1 = 0.f, x2 = 0.f, y2 = 0.f;
            if (k < kept) {
                int idx = klist[k];
                const float4 v = *(const float4*)(boxes + ((size_t)b * PRE_NMS + idx) * 4);
                x1 = v.x; y1 = v.y; x2 = v.z; y2 = v.w;
            }
            out[o + 0] = (float)b;
            out[o + 1] = x1; out[o + 2] = y1; out[o + 3] = x2; out[o + 4] = y2;
        }
    }
#undef LOADROW_T
#undef LOADROW
#undef STEP
}

// Fallback NMS (used only if ws_size is too small for the bitmask).
__global__ __launch_bounds__(1024) void k_nms_out(
    const float* __restrict__ boxes, float* __restrict__ out)
{
    __shared__ float bx1[PRE_NMS], by1[PRE_NMS], bx2[PRE_NMS], by2[PRE_NMS], bar[PRE_NMS];
    __shared__ unsigned rem[(PRE_NMS + 31) / 32];
    __shared__ int kept_idx[POST_NMS];

    int b = blockIdx.x;
    int t = threadIdx.x;

    for (int p = t; p < PRE_NMS; p += 1024) {
        size_t o = ((size_t)b * PRE_NMS + p) * 4;
        float x1 = boxes[o], y1 = boxes[o + 1], x2 = boxes[o + 2], y2 = boxes[o + 3];
        bx1[p] = x1; by1[p] = y1; bx2[p] = x2; by2[p] = y2;
        bar[p] = __fmul_rn(__fadd_rn(__fsub_rn(x2, x1), 1.0f),
                           __fadd_rn(__fsub_rn(y2, y1), 1.0f));
    }
    for (int p = t; p < (PRE_NMS + 31) / 32; p += 1024) rem[p] = 0u;
    __syncthreads();

    int kept = 0;
    for (int i = 0; i < PRE_NMS && kept < POST_NMS; ++i) {
        if (rem[i >> 5] & (1u << (i & 31))) continue;
        if (t == 0) kept_idx[kept] = i;
        float xi1 = bx1[i], yi1 = by1[i], xi2 = bx2[i], yi2 = by2[i], ai = bar[i];
        for (int j = i + 1 + t; j < PRE_NMS; j += 1024) {
            float xx1 = fmaxf(xi1, bx1[j]);
            float yy1 = fmaxf(yi1, by1[j]);
            float xx2 = fminf(xi2, bx2[j]);
            float yy2 = fminf(yi2, by2[j]);
            float iw = fmaxf(0.0f, __fadd_rn(__fsub_rn(xx2, xx1), 1.0f));
            float ih = fmaxf(0.0f, __fadd_rn(__fsub_rn(yy2, yy1), 1.0f));
            float inter = __fmul_rn(iw, ih);
            if (inter > 0.0f) {
                float uni = __fsub_rn(__fadd_rn(ai, bar[j]), inter);
                float iou = __fdiv_rn(inter, uni);
                if (iou > NMS_THRESH_F) atomicOr(&rem[j >> 5], 1u << (j & 31));
            }
        }
        ++kept;
        __syncthreads();
    }

    for (int k = t; k < POST_NMS; k += 1024) {
        size_t o = ((size_t)b * POST_NMS + k) * 5;
        out[o] = (float)b;
        if (k < kept) {
            int ii = kept_idx[k];
            out[o + 1] = bx1[ii]; out[o + 2] = by1[ii];
            out[o + 3] = bx2[ii]; out[o + 4] = by2[ii];
        } else {
            out[o + 1] = 0.0f; out[o + 2] = 0.0f; out[o + 3] = 0.0f; out[o + 4] = 0.0f;
        }
    }
}

extern "C" void kernel_launch(void* const* d_in, const int* in_sizes, int n_in,
                              void* d_out, int out_size, void* d_ws, size_t ws_size,
                              hipStream_t stream)
{
    const float* scores  = (const float*)d_in[0];
    const float* deltas  = (const float*)d_in[1];
    const float* im_info = (const float*)d_in[2];
    const float* anchors = (const float*)d_in[3];
    float* out = (float*)d_out;
    char* ws = (char*)d_ws;

    unsigned* keys             = (unsigned*)(ws + OFF_KEYS);
    unsigned* phist            = (unsigned*)(ws + OFF_PHIST);
    unsigned long long* tmask  = (unsigned long long*)(ws + OFF_TMASK);
    float* boxes               = (float*)(ws + OFF_BOXES);
    unsigned* bbro             = (unsigned*)(ws + OFF_BBRO);
    unsigned* bbmut            = (unsigned*)(ws + OFF_BBMUT);
    unsigned* thresh           = (unsigned*)(ws + OFF_CNT);
    unsigned* cnt              = thresh + 8;
    unsigned long long* seg    = (unsigned long long*)(ws + OFF_SEG);
    unsigned* ridx             = (unsigned*)(ws + OFF_RIDX);
    char* state                = (char*)(ws + OFF_STATE);
    unsigned long long* mask   = (unsigned long long*)(ws + OFF_MASK);

    int total = B_NUM * N_ANCH;
    int blk = 256;
    k_decode<<<(total + blk - 1) / blk, blk, 0, stream>>>(
        scores, deltas, im_info, anchors, keys);
    k_hist_part<<<B_NUM * 4, 1024, 0, stream>>>(keys, phist);
    k_thresh2<<<B_NUM, 1024, 0, stream>>>(phist, bbro, bbmut, thresh, cnt);
    k_scatter<<<(total + blk - 1) / blk, blk, 0, stream>>>(
        keys, thresh, bbmut, seg);
    k_rank<<<B_NUM * 32, 256, 0, stream>>>(seg, cnt, bbro, ridx);
    k_decode2<<<(B_NUM * PRE_NMS + blk - 1) / blk, blk, 0, stream>>>(
        ridx, deltas, im_info, anchors, boxes);

    if (ws_size >= (size_t)OFF_MASK + MASK_BYTES) {
        // phase A: rows 0..1023 only
        k_iou_mask<<<B_NUM * G_HEAD, 256, 0, stream>>>(
            boxes, mask, 0, G_HEAD, (const char*)0);
        // transpose head rows to row-major (overlays dead keys/phist)
        k_transpose<<<B_NUM * R_SPLIT, 1024, 0, stream>>>(mask, tmask);
        // scan p1: early-stop within rows < 1024 (coalesced row loads)
        k_nms_scan_part<<<B_NUM, 64, 0, stream>>>(
            mask, tmask, boxes, out, state, 0, ROWS_SPLIT, 0);
        // tail: rows >= 1024, skipped per batch when done
        k_iou_mask<<<B_NUM * G_TAIL, 256, 0, stream>>>(
            boxes, mask, R_SPLIT, G_TAIL, (const char*)state);
        // scan p2: finish (or just write output if already done)
        k_nms_scan_part<<<B_NUM, 64, 0, stream>>>(
            mask, tmask, boxes, out, state, ROWS_SPLIT, PRE_NMS, 1);
    } else {
        k_nms_out<<<B_NUM, 1024, 0, stream>>>(boxes, out);
    }
}

// Round 24
// 169.303 us; speedup vs baseline: 2.2872x; 1.2107x over previous
//
#include <hip/hip_runtime.h>
#include <stdint.h>

#define FEAT_STRIDE_I 16
#define A_NUM 9
#define HH 128
#define WW 128
#define NPIX (HH * WW)            // 16384
#define N_ANCH (NPIX * A_NUM)     // 147456
#define B_NUM 8
#define PRE_NMS 6000
#define POST_NMS 300
#define NMS_THRESH_F 0.7f
#define MIN_SIZE_F 16.0f
#define NEG_INF_F -1e30f

#define NBS 16384                  // 14-bit bins (key>>18)
#define SWS(i) ((i) + ((i) >> 5))  // LDS swizzle
// cache-line spread for the mutable bin counters: adjacent bins -> 64B apart
// (bijective on 14 bits). Threshold-adjacent hot bins otherwise share 64B
// lines and same-line atomics serialize at the L2 bank (~2500-deep chains).
#define SWB(bin) ((((bin) & 1023) << 4) | ((bin) >> 10))
#define SEGL 8192                  // candidate segment cap (cnt ~6700 max)
#define QKEYS (N_ANCH / 4)         // 36864 keys per hist part

#define RT_TILES 94                // ceil(6000/64)
#define GT_TILES 600               // sum_R ceil((94-R)/8): 8-column groups
#define BQWORDS (RT_TILES * RT_TILES * 64)   // 565,504 qwords per batch

// truncated-IoU split: phase A computes row-tiles R < R_SPLIT (rows 0..1023);
// the tail (R >= R_SPLIT) is skipped per batch when the scan already kept 300.
#define R_SPLIT 16
#define ROWS_SPLIT (R_SPLIT * 64)  // 1024
#define G_HEAD 180                 // sum_{R=0..15} (101-R)>>3
#define G_TAIL (GT_TILES - G_HEAD) // 420
#define STATE_STRIDE 2048          // per-batch scan state (kept,done,supp,klist)
#define TMQ (ROWS_SPLIT * RT_TILES)            // 96,256 qwords per batch

// ---- workspace layout (bytes) ----
// KEYS and PHIST are dead by the time k_transpose runs; the row-major head
// mask (TMASK, 6,160,384 B) overlays them — no extra ws needed.
#define OFF_KEYS    0u             // 8*147456*4 = 4,718,592
#define OFF_PHIST   4718592u       // 8*4*16384*4 = 2,097,152 -> ends 6,815,744
#define OFF_TMASK   0u             // 8*96256*8 = 6,160,384 (overlay, late-use)
#define OFF_BOXES   6815744u       // 8*6000*4*4 = 768,000
#define OFF_BBRO    7583744u       // 8*16384*4 = 524,288 (read-only binbase)
#define OFF_BBMUT   8108032u       // 524,288 (scatter slot counters, swizzled)
#define OFF_CNT     8632320u       // thresh[8] + cnt[8] (512 B)
#define OFF_SEG     8632832u       // 8*8192*8 = 524,288
#define OFF_RIDX    9157120u       // 8*6000*4 = 192,000
#define OFF_STATE   9349120u       // 8*2048 = 16,384
#define OFF_MASK    9365504u       // 36,192,256 -> end 45,557,760
#define MASK_BYTES ((size_t)B_NUM * BQWORDS * 8)

__device__ __forceinline__ unsigned sortable_f32(float f) {
    unsigned u = __float_as_uint(f);
    return (u & 0x80000000u) ? ~u : (u | 0x80000000u);
}

// Decode one anchor's box exactly in the reference's op order.
__device__ __forceinline__ void decode_box(
    int b, int idx,
    const float* __restrict__ deltas, const float* __restrict__ im_info,
    const float* __restrict__ anchors,
    float& x1, float& y1, float& x2, float& y2, bool& valid)
{
    int a   = idx % A_NUM;
    int pix = idx / A_NUM;
    int w   = pix & (WW - 1);
    int h   = pix >> 7;

    float a0 = anchors[a * 4 + 0];
    float a1 = anchors[a * 4 + 1];
    float a2 = anchors[a * 4 + 2];
    float a3 = anchors[a * 4 + 3];

    float aw = __fadd_rn(__fsub_rn(a2, a0), 1.0f);
    float ah = __fadd_rn(__fsub_rn(a3, a1), 1.0f);
    float sx = (float)(w * FEAT_STRIDE_I);
    float sy = (float)(h * FEAT_STRIDE_I);
    float acx = __fadd_rn(__fadd_rn(sx, a0), __fmul_rn(0.5f, aw));
    float acy = __fadd_rn(__fadd_rn(sy, a1), __fmul_rn(0.5f, ah));

    size_t base = ((size_t)b * 36 + 4 * a) * NPIX + pix;
    float dx = deltas[base];
    float dy = deltas[base + NPIX];
    float dw = deltas[base + 2 * (size_t)NPIX];
    float dh = deltas[base + 3 * (size_t)NPIX];

    float pcx = __fadd_rn(__fmul_rn(dx, aw), acx);
    float pcy = __fadd_rn(__fmul_rn(dy, ah), acy);
    float pw  = __fmul_rn(expf(dw), aw);
    float ph  = __fmul_rn(expf(dh), ah);

    float hx = __fmul_rn(0.5f, pw);
    float hy = __fmul_rn(0.5f, ph);
    x1 = __fsub_rn(pcx, hx);
    y1 = __fsub_rn(pcy, hy);
    x2 = __fadd_rn(pcx, hx);
    y2 = __fadd_rn(pcy, hy);

    float im_h = im_info[b * 3 + 0];
    float im_w = im_info[b * 3 + 1];
    float sc   = im_info[b * 3 + 2];
    float wmax = __fsub_rn(im_w, 1.0f);
    float hmax = __fsub_rn(im_h, 1.0f);

    x1 = fminf(fmaxf(x1, 0.0f), wmax);
    y1 = fminf(fmaxf(y1, 0.0f), hmax);
    x2 = fminf(fmaxf(x2, 0.0f), wmax);
    y2 = fminf(fmaxf(y2, 0.0f), hmax);

    float min_sz = __fmul_rn(MIN_SIZE_F, sc);
    valid = (__fadd_rn(__fsub_rn(x2, x1), 1.0f) >= min_sz) &&
            (__fadd_rn(__fsub_rn(y2, y1), 1.0f) >= min_sz);
}

// K1: decode + masked score -> sortable key. Pure streaming, no atomics.
__global__ void k_decode(
    const float* __restrict__ scores, const float* __restrict__ deltas,
    const float* __restrict__ im_info, const float* __restrict__ anchors,
    unsigned* __restrict__ keys)
{
    int gt = blockIdx.x * blockDim.x + threadIdx.x;
    if (gt >= B_NUM * N_ANCH) return;
    int pix  = gt & (NPIX - 1);
    int rest = gt >> 14;
    int a = rest % A_NUM;
    int b = rest / A_NUM;
    int idx = pix * A_NUM + a;

    float x1, y1, x2, y2; bool valid;
    decode_box(b, idx, deltas, im_info, anchors, x1, y1, x2, y2, valid);

    float s = scores[((size_t)b * 18 + 9 + a) * NPIX + pix];
    if (!valid) s = NEG_INF_F;
    keys[gt] = sortable_f32(s);
}

// K2: partial histograms — 4 blocks per batch, each hists one quarter of
// the keys in a private LDS 16384-bin histogram (staged uint4 loads).
__global__ __launch_bounds__(1024) void k_hist_part(
    const unsigned* __restrict__ keys, unsigned* __restrict__ phist)
{
    __shared__ unsigned h[SWS(NBS - 1) + 2];   // 16896 words = 67.6 KB
    int b = blockIdx.x >> 2;
    int p = blockIdx.x & 3;
    int t = threadIdx.x;

    for (int i = t; i < SWS(NBS - 1) + 2; i += 1024) h[i] = 0u;
    __syncthreads();

    const uint4* kb4 = (const uint4*)(keys + (size_t)b * N_ANCH + p * QKEYS);
    uint4 v[9];
    #pragma unroll
    for (int k = 0; k < 9; ++k) v[k] = kb4[t + 1024 * k];
    #pragma unroll
    for (int k = 0; k < 9; ++k) {
        atomicAdd(&h[SWS(v[k].x >> 18)], 1u);
        atomicAdd(&h[SWS(v[k].y >> 18)], 1u);
        atomicAdd(&h[SWS(v[k].z >> 18)], 1u);
        atomicAdd(&h[SWS(v[k].w >> 18)], 1u);
    }
    __syncthreads();

    unsigned* ph = phist + (size_t)blockIdx.x * NBS;
    for (int i = t; i < NBS; i += 1024) ph[i] = h[SWS(i)];
}

// K3: per batch — sum 4 partials, suffix-scan 16384 bins, find threshold T.
// bbro is linear (read by k_rank); bbmut is written at SWB-swizzled indices
// so k_scatter's hot-bin atomics spread across cache lines.
__global__ __launch_bounds__(1024) void k_thresh2(
    const unsigned* __restrict__ phist, unsigned* __restrict__ bbro,
    unsigned* __restrict__ bbmut, unsigned* __restrict__ thresh,
    unsigned* __restrict__ cnt)
{
    __shared__ unsigned h[SWS(NBS - 1) + 2];
    __shared__ unsigned csum[1024];
    __shared__ unsigned sT;

    int b = blockIdx.x;
    int t = threadIdx.x;
    if (t == 0) sT = 0;

    const unsigned* ph = phist + (size_t)b * 4 * NBS;
    for (int i = t; i < NBS; i += 1024) {
        unsigned s0 = ph[i];
        unsigned s1 = ph[NBS + i];
        unsigned s2 = ph[2 * NBS + i];
        unsigned s3 = ph[3 * NBS + i];
        h[SWS(i)] = s0 + s1 + s2 + s3;
    }
    __syncthreads();

    int base = t * 16;
    unsigned s = 0;
    for (int u = 0; u < 16; ++u) s += h[SWS(base + u)];
    csum[t] = s;
    __syncthreads();
    for (int off = 1; off < 1024; off <<= 1) {
        unsigned v = (t + off < 1024) ? csum[t + off] : 0u;
        __syncthreads();
        csum[t] += v;
        __syncthreads();
    }
    unsigned before = csum[t] - s;

    unsigned acc = before;
    for (int bin = base + 15; bin >= base; --bin) {
        unsigned hh = h[SWS(bin)];
        if (acc + hh >= PRE_NMS) { atomicMax(&sT, (unsigned)bin); break; }
        acc += hh;
    }
    __syncthreads();
    unsigned T = sT;

    acc = before;
    for (int bin = base + 15; bin >= base; --bin) {
        unsigned hh = h[SWS(bin)];
        if ((unsigned)bin == T) cnt[b] = acc + hh;
        h[SWS(bin)] = acc;
        acc += hh;
    }
    if (t == 0) thresh[b] = T;
    __syncthreads();

    unsigned* r = bbro + (size_t)b * NBS;
    unsigned* m = bbmut + (size_t)b * NBS;
    for (int i = t; i < NBS; i += 1024) {
        unsigned v = h[SWS(i)];
        r[i] = v;
        m[SWB(i)] = v;
    }
}

// K4: bin-segmented scatter — slot allocated by atomicAdd on the SWIZZLED
// mutable binbase copy (adjacent hot bins no longer share cache lines; the
// measured 60us was same-line atomic serialization at the L2 bank).
__global__ void k_scatter(
    const unsigned* __restrict__ keys, const unsigned* __restrict__ thresh,
    unsigned* __restrict__ bbmut, unsigned long long* __restrict__ seg)
{
    int gt = blockIdx.x * blockDim.x + threadIdx.x;
    int pix  = gt & (NPIX - 1);
    int rest = gt >> 14;
    int a = rest % A_NUM;
    int b = rest / A_NUM;

    unsigned key = keys[gt];
    unsigned bin = key >> 18;
    if (bin >= thresh[b]) {
        unsigned pos = atomicAdd(&bbmut[(size_t)b * NBS + SWB(bin)], 1u);
        if (pos < SEGL) {
            unsigned idx = (unsigned)(pix * A_NUM + a);
            seg[(size_t)b * SEGL + pos] =
                ((unsigned long long)key << 32) | (unsigned long long)(0xFFFFFFFFu - idx);
        }
    }
}

// K5a: many-block counting rank (32 blocks x 256 thr per batch, all CUs).
__global__ __launch_bounds__(256) void k_rank(
    const unsigned long long* __restrict__ seg, const unsigned* __restrict__ cnt,
    const unsigned* __restrict__ bbro, unsigned* __restrict__ ridx)
{
    int b = blockIdx.x >> 5;
    int p = ((blockIdx.x & 31) << 8) + threadIdx.x;
    unsigned n = cnt[b];
    if (n > SEGL) n = SEGL;
    if (p >= (int)n) return;

    const unsigned long long* S = seg + (size_t)b * SEGL;
    unsigned long long key = S[p];
    unsigned bin = (unsigned)(key >> 50);
    const unsigned* bb = bbro + (size_t)b * NBS;
    unsigned base = bb[bin];
    unsigned end = (bin > 0) ? bb[bin - 1] : n;
    if (end > n) end = n;

    unsigned rank = base;
    unsigned q = base;
    for (; q + 8 <= end; q += 8) {
        unsigned long long v0 = S[q + 0], v1 = S[q + 1];
        unsigned long long v2 = S[q + 2], v3 = S[q + 3];
        unsigned long long v4 = S[q + 4], v5 = S[q + 5];
        unsigned long long v6 = S[q + 6], v7 = S[q + 7];
        rank += (unsigned)(v0 > key) + (unsigned)(v1 > key)
              + (unsigned)(v2 > key) + (unsigned)(v3 > key)
              + (unsigned)(v4 > key) + (unsigned)(v5 > key)
              + (unsigned)(v6 > key) + (unsigned)(v7 > key);
    }
    for (; q < end; ++q) rank += (unsigned)(S[q] > key);

    if (rank < PRE_NMS)
        ridx[(size_t)b * PRE_NMS + rank] = 0xFFFFFFFFu - (unsigned)(key & 0xFFFFFFFFull);
}

// K5b: decode one box per output rank across all CUs.
__global__ void k_decode2(
    const unsigned* __restrict__ ridx,
    const float* __restrict__ deltas, const float* __restrict__ im_info,
    const float* __restrict__ anchors, float* __restrict__ boxes)
{
    int gt = blockIdx.x * blockDim.x + threadIdx.x;
    if (gt >= B_NUM * PRE_NMS) return;
    int b = gt / PRE_NMS;
    int idx = (int)ridx[gt];
    float x1, y1, x2, y2; bool v;
    decode_box(b, idx, deltas, im_info, anchors, x1, y1, x2, y2, v);
    *(float4*)(boxes + (size_t)gt * 4) = make_float4(x1, y1, x2, y2);
}

// One row of a 64x64 suppression block (exact ref op order; div only in the
// proven +-6e-7*uni band — validated absmax=0 since round 6).
__device__ __forceinline__ unsigned long long iou_row(
    float4 bi, float ia, float jx1, float jy1, float jx2, float jy2, float ja)
{
    float xx1 = fmaxf(bi.x, jx1);
    float yy1 = fmaxf(bi.y, jy1);
    float xx2 = fminf(bi.z, jx2);
    float yy2 = fminf(bi.w, jy2);
    float iw = fmaxf(0.0f, __fadd_rn(__fsub_rn(xx2, xx1), 1.0f));
    float ih = fmaxf(0.0f, __fadd_rn(__fsub_rn(yy2, yy1), 1.0f));
    float inter = __fmul_rn(iw, ih);
    float uni = __fsub_rn(__fadd_rn(ia, ja), inter);
    float diff = __fsub_rn(inter, __fmul_rn(NMS_THRESH_F, uni));
    unsigned long long sup = __ballot(diff > 0.0f);
    unsigned long long band = __ballot(fabsf(diff) <= __fmul_rn(6e-7f, uni));
    if (band) {
        unsigned long long supd = __ballot(__fdiv_rn(inter, uni) > NMS_THRESH_F);
        sup = (sup & ~band) | (supd & band);
    }
    return sup;
}

// K6: IoU suppression bitmask for row-tiles R in [Rstart, ...), ngroups
// 8-column groups per batch. statep!=null: skip batch if its scan already
// finished (done flag). Layout mask[b][R][C][64].
__global__ __launch_bounds__(256) void k_iou_mask(
    const float* __restrict__ boxes, unsigned long long* __restrict__ mask,
    int Rstart, int ngroups, const char* __restrict__ statep)
{
    int bid = blockIdx.x;
    int b = bid / ngroups;
    int g = bid - b * ngroups;
    if (statep && ((const int*)(statep + (size_t)b * STATE_STRIDE))[1]) return;

    int R = Rstart;
    while (g >= ((RT_TILES - R + 7) >> 3)) { g -= (RT_TILES - R + 7) >> 3; ++R; }

    int wave = threadIdx.x >> 6;
    int lane = threadIdx.x & 63;
    const float* Bb = boxes + (size_t)b * PRE_NMS * 4;

    __shared__ float4 rb4[64];
    __shared__ float rba[64];
    if (threadIdx.x < 64) {
        int il = R * 64 + threadIdx.x;
        float4 rv = make_float4(0.f, 0.f, -1.f, -1.f);
        if (il < PRE_NMS) rv = *(const float4*)(Bb + 4 * (size_t)il);
        rb4[threadIdx.x] = rv;
        rba[threadIdx.x] = __fmul_rn(__fadd_rn(__fsub_rn(rv.z, rv.x), 1.0f),
                                     __fadd_rn(__fsub_rn(rv.w, rv.y), 1.0f));
    }
    __syncthreads();

    int C1 = R + g * 8 + wave * 2;
    int C2 = C1 + 1;
    if (C1 >= RT_TILES) return;   // tail waves idle (no barriers below)

    float j1x1 = 0.f, j1y1 = 0.f, j1x2 = -1.f, j1y2 = -1.f;
    float j2x1 = 0.f, j2y1 = 0.f, j2x2 = -1.f, j2y2 = -1.f;
    int j1 = C1 * 64 + lane;
    int j2 = C2 * 64 + lane;
    if (j1 < PRE_NMS) {
        float4 v = *(const float4*)(Bb + 4 * (size_t)j1);
        j1x1 = v.x; j1y1 = v.y; j1x2 = v.z; j1y2 = v.w;
    }
    if (C2 < RT_TILES && j2 < PRE_NMS) {
        float4 v = *(const float4*)(Bb + 4 * (size_t)j2);
        j2x1 = v.x; j2y1 = v.y; j2x2 = v.z; j2y2 = v.w;
    }
    float j1a = __fmul_rn(__fadd_rn(__fsub_rn(j1x2, j1x1), 1.0f),
                          __fadd_rn(__fsub_rn(j1y2, j1y1), 1.0f));
    float j2a = __fmul_rn(__fadd_rn(__fsub_rn(j2x2, j2x1), 1.0f),
                          __fadd_rn(__fsub_rn(j2y2, j2y1), 1.0f));

    unsigned long long w1 = 0ULL, w2 = 0ULL;
    if (C1 == R) {   // diagonal tile
        #pragma unroll 4
        for (int ri = 0; ri < 64; ++ri) {
            float4 bi = rb4[ri];
            float ia = rba[ri];
            unsigned long long s1 = iou_row(bi, ia, j1x1, j1y1, j1x2, j1y2, j1a)
                                    & (0xFFFFFFFFFFFFFFFEull << ri);
            unsigned long long s2 = iou_row(bi, ia, j2x1, j2y1, j2x2, j2y2, j2a);
            w1 = (lane == ri) ? s1 : w1;
            w2 = (lane == ri) ? s2 : w2;
        }
    } else {
        #pragma unroll 4
        for (int ri = 0; ri < 64; ++ri) {
            float4 bi = rb4[ri];
            float ia = rba[ri];
            unsigned long long s1 = iou_row(bi, ia, j1x1, j1y1, j1x2, j1y2, j1a);
            unsigned long long s2 = iou_row(bi, ia, j2x1, j2y1, j2x2, j2y2, j2a);
            w1 = (lane == ri) ? s1 : w1;
            w2 = (lane == ri) ? s2 : w2;
        }
    }

    unsigned long long* Mb = mask + (size_t)b * BQWORDS;
    Mb[(size_t)(R * RT_TILES + C1) * 64 + lane] = w1;
    if (C2 < RT_TILES)
        Mb[(size_t)(R * RT_TILES + C2) * 64 + lane] = w2;
}

// K6b: transpose head mask [R][C][64] -> row-major tmask[i][C] for rows
// < ROWS_SPLIT (scan p1's rows become 94 contiguous qwords = 12 lines).
__global__ __launch_bounds__(1024) void k_transpose(
    const unsigned long long* __restrict__ mask,
    unsigned long long* __restrict__ tmask)
{
    __shared__ unsigned long long tile[64 * RT_TILES];   // 48,128 B
    int b = blockIdx.x >> 4;
    int R = blockIdx.x & 15;
    int t = threadIdx.x;
    const unsigned long long* Mb =
        mask + (size_t)b * BQWORDS + (size_t)R * RT_TILES * 64;
    for (int idx = t; idx < RT_TILES * 64; idx += 1024) {
        int C = idx >> 6, r = idx & 63;
        tile[r * RT_TILES + C] = Mb[(size_t)C * 64 + r];
    }
    __syncthreads();
    unsigned long long* Tb =
        tmask + (size_t)b * TMQ + (size_t)R * 64 * RT_TILES;
    for (int idx = t; idx < 64 * RT_TILES; idx += 1024)
        Tb[idx] = tile[idx];
}

// K7: greedy scan, resumable. One wave/batch. Suppression state in
// registers (lane l owns words l, 64+l); curw via cross-lane shuffle.
// p1 (final_phase==0) reads the ROW-MAJOR tmask; p2 the original layout.
__global__ __launch_bounds__(64) void k_nms_scan_part(
    const unsigned long long* __restrict__ mask,
    const unsigned long long* __restrict__ tmask,
    const float* __restrict__ boxes, float* __restrict__ out,
    char* __restrict__ statep, int row_begin, int row_end, int final_phase)
{
    const int b = blockIdx.x;
    const int l = threadIdx.x;
    char* st = statep + (size_t)b * STATE_STRIDE;
    int* s_meta = (int*)st;
    unsigned long long* s_supp = (unsigned long long*)(st + 16);
    int* s_klist = (int*)(st + 768);

    __shared__ int klist[POST_NMS];
    unsigned long long reg0, reg1;   // suppression words l and 64+l
    int kept, done;

    if (row_begin == 0) {
        reg0 = 0ULL; reg1 = 0ULL;
        kept = 0; done = 0;
    } else {
        kept = s_meta[0];
        done = s_meta[1];
        reg0 = s_supp[l];
        reg1 = (l < RT_TILES - 64) ? s_supp[64 + l] : 0ULL;
        for (int k = l; k < POST_NMS; k += 64) klist[k] = s_klist[k];
    }
    __syncthreads();

    const unsigned long long* __restrict__ M = mask + (size_t)b * BQWORDS;
    const unsigned long long* __restrict__ TM = tmask + (size_t)b * TMQ;
    unsigned long long curw = 0; int curwi = -1;

#define LOADROW_T(p0, p1, i) { \
        int _i = ((i) < ROWS_SPLIT) ? (i) : (ROWS_SPLIT - 1); \
        const unsigned long long* _r = TM + (size_t)_i * RT_TILES; \
        p0 = _r[l]; \
        p1 = (l < RT_TILES - 64) ? _r[64 + l] : 0ULL; }

#define LOADROW(p0, p1, i) { \
        int _i = ((i) < PRE_NMS) ? (i) : (PRE_NMS - 1); \
        int _R = _i >> 6; \
        const unsigned long long* _r = M + (size_t)(_R * RT_TILES) * 64 + (_i & 63); \
        p0 = 0ULL; p1 = 0ULL; \
        if (l >= _R) p0 = _r[l * 64]; \
        if (l < RT_TILES - 64 && 64 + l >= _R) p1 = _r[(64 + l) * 64]; }

#define STEP(i, p0, p1) { \
        if (kept < POST_NMS) { \
            int _wi = (i) >> 6; \
            if (_wi != curwi) { \
                curw = (_wi < 64) ? __shfl(reg0, _wi) : __shfl(reg1, _wi - 64); \
                curwi = _wi; \
            } \
            if (!((curw >> ((i) & 63)) & 1ULL)) { \
                if (l == 0) klist[kept] = (i); \
                unsigned long long _d = (_wi < 64) ? __shfl(p0, _wi) \
                                                   : __shfl(p1, _wi - 64); \
                reg0 |= p0; \
                reg1 |= p1; \
                curw |= _d; \
                ++kept; \
            } \
        } }

    if (!done && kept < POST_NMS) {
        unsigned long long p[16][2];
        if (!final_phase) {
            #pragma unroll
            for (int k = 0; k < 16; ++k) { LOADROW_T(p[k][0], p[k][1], row_begin + k) }
            for (int i = row_begin; i < row_end && kept < POST_NMS; i += 16) {
                #pragma unroll
                for (int k = 0; k < 16; ++k) {
                    STEP(i + k, p[k][0], p[k][1])
                    LOADROW_T(p[k][0], p[k][1], i + 16 + k)
                }
            }
        } else {
            #pragma unroll
            for (int k = 0; k < 16; ++k) { LOADROW(p[k][0], p[k][1], row_begin + k) }
            for (int i = row_begin; i < row_end && kept < POST_NMS; i += 16) {
                #pragma unroll
                for (int k = 0; k < 16; ++k) {
                    STEP(i + k, p[k][0], p[k][1])
                    LOADROW(p[k][0], p[k][1], i + 16 + k)
                }
            }
        }
    }
    __syncthreads();

    if (!final_phase) {
        if (l == 0) { s_meta[0] = kept; s_meta[1] = (kept >= POST_NMS) ? 1 : 0; }
        s_supp[l] = reg0;
        if (l < RT_TILES - 64) s_supp[64 + l] = reg1;
        for (int k = l; k < POST_NMS; k += 64) s_klist[k] = klist[k];
    } else {
        for (int k = l; k < POST_NMS; k += 64) {
            size_t o = ((size_t)b * POST_NMS + k) * 5;
            float x1 = 0.f, y1 = 0.f, x2 = 0.f, y2 = 0.f;
            if (k < kept) {
                int idx = klist[k];
                const float4 v = *(const float4*)(boxes + ((size_t)b * PRE_NMS + idx) * 4);
                x1 = v.x; y1 = v.y; x2 = v.z; y2 = v.w;
            }
            out[o + 0] = (float)b;
            out[o + 1] = x1; out[o + 2] = y1; out[o + 3] = x2; out[o + 4] = y2;
        }
    }
#undef LOADROW_T
#undef LOADROW
#undef STEP
}

// Fallback NMS (used only if ws_size is too small for the bitmask).
__global__ __launch_bounds__(1024) void k_nms_out(
    const float* __restrict__ boxes, float* __restrict__ out)
{
    __shared__ float bx1[PRE_NMS], by1[PRE_NMS], bx2[PRE_NMS], by2[PRE_NMS], bar[PRE_NMS];
    __shared__ unsigned rem[(PRE_NMS + 31) / 32];
    __shared__ int kept_idx[POST_NMS];

    int b = blockIdx.x;
    int t = threadIdx.x;

    for (int p = t; p < PRE_NMS; p += 1024) {
        size_t o = ((size_t)b * PRE_NMS + p) * 4;
        float x1 = boxes[o], y1 = boxes[o + 1], x2 = boxes[o + 2], y2 = boxes[o + 3];
        bx1[p] = x1; by1[p] = y1; bx2[p] = x2; by2[p] = y2;
        bar[p] = __fmul_rn(__fadd_rn(__fsub_rn(x2, x1), 1.0f),
                           __fadd_rn(__fsub_rn(y2, y1), 1.0f));
    }
    for (int p = t; p < (PRE_NMS + 31) / 32; p += 1024) rem[p] = 0u;
    __syncthreads();

    int kept = 0;
    for (int i = 0; i < PRE_NMS && kept < POST_NMS; ++i) {
        if (rem[i >> 5] & (1u << (i & 31))) continue;
        if (t == 0) kept_idx[kept] = i;
        float xi1 = bx1[i], yi1 = by1[i], xi2 = bx2[i], yi2 = by2[i], ai = bar[i];
        for (int j = i + 1 + t; j < PRE_NMS; j += 1024) {
            float xx1 = fmaxf(xi1, bx1[j]);
            float yy1 = fmaxf(yi1, by1[j]);
            float xx2 = fminf(xi2, bx2[j]);
            float yy2 = fminf(yi2, by2[j]);
            float iw = fmaxf(0.0f, __fadd_rn(__fsub_rn(xx2, xx1), 1.0f));
            float ih = fmaxf(0.0f, __fadd_rn(__fsub_rn(yy2, yy1), 1.0f));
            float inter = __fmul_rn(iw, ih);
            if (inter > 0.0f) {
                float uni = __fsub_rn(__fadd_rn(ai, bar[j]), inter);
                float iou = __fdiv_rn(inter, uni);
                if (iou > NMS_THRESH_F) atomicOr(&rem[j >> 5], 1u << (j & 31));
            }
        }
        ++kept;
        __syncthreads();
    }

    for (int k = t; k < POST_NMS; k += 1024) {
        size_t o = ((size_t)b * POST_NMS + k) * 5;
        out[o] = (float)b;
        if (k < kept) {
            int ii = kept_idx[k];
            out[o + 1] = bx1[ii]; out[o + 2] = by1[ii];
            out[o + 3] = bx2[ii]; out[o + 4] = by2[ii];
        } else {
            out[o + 1] = 0.0f; out[o + 2] = 0.0f; out[o + 3] = 0.0f; out[o + 4] = 0.0f;
        }
    }
}

extern "C" void kernel_launch(void* const* d_in, const int* in_sizes, int n_in,
                              void* d_out, int out_size, void* d_ws, size_t ws_size,
                              hipStream_t stream)
{
    const float* scores  = (const float*)d_in[0];
    const float* deltas  = (const float*)d_in[1];
    const float* im_info = (const float*)d_in[2];
    const float* anchors = (const float*)d_in[3];
    float* out = (float*)d_out;
    char* ws = (char*)d_ws;

    unsigned* keys             = (unsigned*)(ws + OFF_KEYS);
    unsigned* phist            = (unsigned*)(ws + OFF_PHIST);
    unsigned long long* tmask  = (unsigned long long*)(ws + OFF_TMASK);
    float* boxes               = (float*)(ws + OFF_BOXES);
    unsigned* bbro             = (unsigned*)(ws + OFF_BBRO);
    unsigned* bbmut            = (unsigned*)(ws + OFF_BBMUT);
    unsigned* thresh           = (unsigned*)(ws + OFF_CNT);
    unsigned* cnt              = thresh + 8;
    unsigned long long* seg    = (unsigned long long*)(ws + OFF_SEG);
    unsigned* ridx             = (unsigned*)(ws + OFF_RIDX);
    char* state                = (char*)(ws + OFF_STATE);
    unsigned long long* mask   = (unsigned long long*)(ws + OFF_MASK);

    int total = B_NUM * N_ANCH;
    int blk = 256;
    k_decode<<<(total + blk - 1) / blk, blk, 0, stream>>>(
        scores, deltas, im_info, anchors, keys);
    k_hist_part<<<B_NUM * 4, 1024, 0, stream>>>(keys, phist);
    k_thresh2<<<B_NUM, 1024, 0, stream>>>(phist, bbro, bbmut, thresh, cnt);
    k_scatter<<<(total + blk - 1) / blk, blk, 0, stream>>>(
        keys, thresh, bbmut, seg);
    k_rank<<<B_NUM * 32, 256, 0, stream>>>(seg, cnt, bbro, ridx);
    k_decode2<<<(B_NUM * PRE_NMS + blk - 1) / blk, blk, 0, stream>>>(
        ridx, deltas, im_info, anchors, boxes);

    if (ws_size >= (size_t)OFF_MASK + MASK_BYTES) {
        // phase A: rows 0..1023 only
        k_iou_mask<<<B_NUM * G_HEAD, 256, 0, stream>>>(
            boxes, mask, 0, G_HEAD, (const char*)0);
        // transpose head rows to row-major (overlays dead keys/phist)
        k_transpose<<<B_NUM * R_SPLIT, 1024, 0, stream>>>(mask, tmask);
        // scan p1: early-stop within rows < 1024 (coalesced row loads)
        k_nms_scan_part<<<B_NUM, 64, 0, stream>>>(
            mask, tmask, boxes, out, state, 0, ROWS_SPLIT, 0);
        // tail: rows >= 1024, skipped per batch when done
        k_iou_mask<<<B_NUM * G_TAIL, 256, 0, stream>>>(
            boxes, mask, R_SPLIT, G_TAIL, (const char*)state);
        // scan p2: finish (or just write output if already done)
        k_nms_scan_part<<<B_NUM, 64, 0, stream>>>(
            mask, tmask, boxes, out, state, ROWS_SPLIT, PRE_NMS, 1);
    } else {
        k_nms_out<<<B_NUM, 1024, 0, stream>>>(boxes, out);
    }
}